// Round 2
// baseline (978.102 us; speedup 1.0000x reference)
//
#include <hip/hip_runtime.h>
#include <cmath>

#pragma clang fp contract(off)

typedef unsigned int u32;
typedef unsigned long long u64;

#define K_PER_LVL 1000
#define KTOT 5000            // 5 levels * 1000
#define NIMG 2
#define MASK_STRIDE 80       // u64 words per mask row (79 used, 1 pad)
#define EQ_CAP 256

__constant__ int c_LG[5] = {512, 256, 128, 64, 32};      // grid dim (square)
__constant__ int c_LS[5] = {4, 8, 16, 32, 64};           // stride
__constant__ int c_LZ[5] = {32, 64, 128, 256, 512};      // anchor size
__constant__ int c_LM[5] = {786432, 196608, 49152, 12288, 3072}; // 3*G*G

struct Ptrs { const float* o[5]; const float* b[5]; };

// monotone float -> uint key (larger float => larger key)
__device__ inline u32 fkey(float f) {
    u32 u = __float_as_uint(f);
    return (u & 0x80000000u) ? ~u : (u | 0x80000000u);
}

// ---------------- init ----------------
__global__ void k_init(u32* hist, u32* prefix, int* kneed, u32* gcnt, u32* ecnt) {
    int t = threadIdx.x;
    for (int i = t; i < 2560; i += 64) hist[i] = 0;
    if (t < 10) { prefix[t] = 0; kneed[t] = K_PER_LVL; gcnt[t] = 0; ecnt[t] = 0; }
}

// ---------------- radix-select histogram pass ----------------
__global__ void k_hist(Ptrs P, u32* __restrict__ hist, const u32* __restrict__ prefix, int pass) {
    int p = blockIdx.y; int l = p % 5; int n = p / 5;
    int M = c_LM[l];
    const float* base = P.o[l] + (size_t)n * M;
    __shared__ u32 lh[256];
    lh[threadIdx.x] = 0;
    __syncthreads();
    int shift = 24 - 8 * pass;
    int hi = (pass == 0) ? 31 : (shift + 8);
    u32 pref = prefix[p];
    int stride = gridDim.x * 256;
    for (int i = blockIdx.x * 256 + threadIdx.x; i < M; i += stride) {
        u32 k = fkey(base[i]);
        bool ok = (pass == 0) || ((k >> hi) == (pref >> hi));
        if (ok) atomicAdd(&lh[(k >> shift) & 255], 1u);
    }
    __syncthreads();
    u32 c = lh[threadIdx.x];
    if (c) atomicAdd(&hist[p * 256 + threadIdx.x], c);
}

// ---------------- radix-select resolve ----------------
__global__ void k_resolve(u32* hist, u32* prefix, int* kneed, int pass) {
    int t = threadIdx.x;
    if (t < 10) {
        int K = kneed[t];
        u32 G = 0; int B = 0;
        for (int b = 255; b >= 0; --b) {
            u32 c = hist[t * 256 + b];
            if (G + c >= (u32)K) { B = b; break; }
            G += c;
        }
        int shift = 24 - 8 * pass;
        prefix[t] |= ((u32)B) << shift;
        kneed[t] = K - (int)G;
    }
    __syncthreads();
    if (pass < 3) {
        for (int i = t; i < 2560; i += 64) hist[i] = 0;
    }
}

// ---------------- compact: >T -> sel front; ==T -> eq buffer ----------------
__global__ void k_compact(Ptrs P, const u32* __restrict__ prefix,
                          u32* gcnt, u32* ecnt, int* __restrict__ sel, int* __restrict__ eq) {
    int p = blockIdx.y; int l = p % 5; int n = p / 5;
    int M = c_LM[l]; int gg = M / 3;
    const float* base = P.o[l] + (size_t)n * M;
    u32 T = prefix[p];
    int stride = gridDim.x * 256;
    for (int i = blockIdx.x * 256 + threadIdx.x; i < M; i += stride) {
        u32 k = fkey(base[i]);
        if (k < T) continue;
        // input linear i = a*gg + pix ; flattened m = pix*3 + a  (h,w,a order)
        int a = i / gg; int pix = i - a * gg; int m = pix * 3 + a;
        if (k > T) {
            u32 pos = atomicAdd(&gcnt[p], 1u);
            sel[p * K_PER_LVL + pos] = m;
        } else {
            u32 e = atomicAdd(&ecnt[p], 1u);
            if (e < EQ_CAP) eq[p * EQ_CAP + e] = m;
        }
    }
}

// ---------------- boundary ties: pick KF lowest flat-indices (top_k tie rule) ----------------
__global__ void k_eqsel(const u32* __restrict__ ecnt, const int* __restrict__ kneed,
                        int* eq, int* __restrict__ sel) {
    int p = blockIdx.x;
    if (threadIdx.x != 0) return;
    int E = (int)ecnt[p]; if (E > EQ_CAP) E = EQ_CAP;
    int KF = kneed[p];
    int G0 = K_PER_LVL - KF;
    int* e = eq + p * EQ_CAP;
    for (int r = 0; r < KF && r < E; ++r) {       // partial selection sort, ascending m
        int mi = r;
        for (int q = r + 1; q < E; ++q) if (e[q] < e[mi]) mi = q;
        int t = e[mi]; e[mi] = e[r]; e[r] = t;
        sel[p * K_PER_LVL + G0 + r] = t;
    }
}

// ---------------- featurize: anchors + decode + clip + score + 64b order key ----------------
__global__ void k_feat(Ptrs P, const int* __restrict__ sel, u64* __restrict__ key64,
                       float* __restrict__ csc, float* __restrict__ cbox, float* __restrict__ cobox) {
    int tid = blockIdx.x * 256 + threadIdx.x;
    if (tid >= NIMG * KTOT) return;
    int p = tid / K_PER_LVL, s = tid - p * K_PER_LVL;
    int n = p / 5, l = p % 5;
    int G = c_LG[l], S = c_LS[l], Z = c_LZ[l];
    int gg = G * G;
    int m = sel[p * K_PER_LVL + s];
    int a = m % 3; int pix = m / 3; int h = pix / G; int w = pix - h * G;

    // anchor base: hr=sqrt(ar), wr=1/hr, round-half-even (matches jnp f32)
    const float ars[3] = {0.5f, 1.0f, 2.0f};
    float ar = ars[a];
    float hr = sqrtf(ar), wr = 1.0f / hr;
    float wsz = wr * (float)Z, hsz = hr * (float)Z;
    float bx1 = rintf(-0.5f * wsz), by1 = rintf(-0.5f * hsz);
    float bx2 = rintf(0.5f * wsz),  by2 = rintf(0.5f * hsz);
    float sx = (float)(w * S), sy = (float)(h * S);
    float ax1 = sx + bx1, ay1 = sy + by1, ax2 = sx + bx2, ay2 = sy + by2;
    float wa = ax2 - ax1, ha = ay2 - ay1;
    float cxa = ax1 + 0.5f * wa, cya = ay1 + 0.5f * ha;

    const float* bb = P.b[l] + (size_t)n * 12 * gg;
    float dx = bb[(a * 4 + 0) * gg + pix];
    float dy = bb[(a * 4 + 1) * gg + pix];
    const float CLIPV = 4.135166556742356f;  // log(1000/16)
    float dw = fminf(bb[(a * 4 + 2) * gg + pix], CLIPV);
    float dh = fminf(bb[(a * 4 + 3) * gg + pix], CLIPV);
    float cx = dx * wa + cxa, cy = dy * ha + cya;
    float ww = expf(dw) * wa, hh = expf(dh) * ha;
    float x1 = cx - 0.5f * ww, y1 = cy - 0.5f * hh;
    float x2 = cx + 0.5f * ww, y2 = cy + 0.5f * hh;
    x1 = fminf(fmaxf(x1, 0.f), 2048.f);
    y1 = fminf(fmaxf(y1, 0.f), 2048.f);
    x2 = fminf(fmaxf(x2, 0.f), 2048.f);
    y2 = fminf(fmaxf(y2, 0.f), 2048.f);

    float raw = P.o[l][(size_t)n * 3 * gg + a * gg + pix];
    float sc = 1.0f / (1.0f + expf(-raw));
    bool keep = (x2 - x1 >= 1e-3f) && (y2 - y1 >= 1e-3f) && (sc > 0.0f);

    int slot = n * KTOT + l * K_PER_LVL + s;
    // total order key: raw desc, then (level asc, m asc) == reference concat-position order
    u32 tb = ((u32)l << 20) | (u32)m;          // m < 2^20, l < 8  -> 23 bits, unique
    u32 kk = keep ? fkey(raw) : 0u;            // invalid sinks below every valid (finite raw)
    key64[slot] = ((u64)kk << 23) | (u64)(tb ^ 0x7FFFFFu);

    csc[slot] = keep ? sc : -INFINITY;
    cbox[slot * 4 + 0] = x1; cbox[slot * 4 + 1] = y1;
    cbox[slot * 4 + 2] = x2; cbox[slot * 4 + 3] = y2;
    float off = 4097.0f * (float)l;            // lvl * (W+H+1), batched_nms offset
    cobox[slot * 4 + 0] = x1 + off; cobox[slot * 4 + 1] = y1 + off;
    cobox[slot * 4 + 2] = x2 + off; cobox[slot * 4 + 3] = y2 + off;
}

// ---------------- exact rank by counting (keys unique -> permutation), scatter ----------------
__global__ void k_rank(const u64* __restrict__ key64, const float* __restrict__ csc,
                       const float* __restrict__ cbox, const float* __restrict__ cobox,
                       float* __restrict__ ssc, float* __restrict__ sbox, float* __restrict__ sobox) {
    int n = blockIdx.y;
    int i = blockIdx.x * 256 + threadIdx.x;
    if (i >= KTOT) return;
    const u64* kb = key64 + (size_t)n * KTOT;
    u64 ki = kb[i];
    int rank = 0;
    for (int j = 0; j < KTOT; ++j) rank += (kb[j] > ki) ? 1 : 0;
    int src = n * KTOT + i, dst = n * KTOT + rank;
    ssc[dst] = csc[src];
    sbox[dst * 4 + 0] = cbox[src * 4 + 0]; sbox[dst * 4 + 1] = cbox[src * 4 + 1];
    sbox[dst * 4 + 2] = cbox[src * 4 + 2]; sbox[dst * 4 + 3] = cbox[src * 4 + 3];
    sobox[dst * 4 + 0] = cobox[src * 4 + 0]; sobox[dst * 4 + 1] = cobox[src * 4 + 1];
    sobox[dst * 4 + 2] = cobox[src * 4 + 2]; sobox[dst * 4 + 3] = cobox[src * 4 + 3];
}

// ---------------- IoU suppression bitmask matrix ----------------
__global__ void k_mask(const float* __restrict__ sobox, u64* __restrict__ mask) {
    int n = blockIdx.z;
    int i = blockIdx.x * 64 + threadIdx.x;
    int j0 = blockIdx.y * 64;
    __shared__ float cb[64][4];
    int jl = j0 + threadIdx.x;
    if (jl < KTOT) {
        cb[threadIdx.x][0] = sobox[(size_t)(n * KTOT + jl) * 4 + 0];
        cb[threadIdx.x][1] = sobox[(size_t)(n * KTOT + jl) * 4 + 1];
        cb[threadIdx.x][2] = sobox[(size_t)(n * KTOT + jl) * 4 + 2];
        cb[threadIdx.x][3] = sobox[(size_t)(n * KTOT + jl) * 4 + 3];
    } else {
        cb[threadIdx.x][0] = 0.f; cb[threadIdx.x][1] = 0.f;
        cb[threadIdx.x][2] = 0.f; cb[threadIdx.x][3] = 0.f;
    }
    __syncthreads();
    if (i >= KTOT) return;
    float x1 = sobox[(size_t)(n * KTOT + i) * 4 + 0];
    float y1 = sobox[(size_t)(n * KTOT + i) * 4 + 1];
    float x2 = sobox[(size_t)(n * KTOT + i) * 4 + 2];
    float y2 = sobox[(size_t)(n * KTOT + i) * 4 + 3];
    float areai = fmaxf(x2 - x1, 0.f) * fmaxf(y2 - y1, 0.f);
    u64 bits = 0;
    int lim = KTOT - j0; if (lim > 64) lim = 64;
    for (int jj = 0; jj < lim; ++jj) {
        float bx1 = cb[jj][0], by1 = cb[jj][1], bx2 = cb[jj][2], by2 = cb[jj][3];
        float areaj = fmaxf(bx2 - bx1, 0.f) * fmaxf(by2 - by1, 0.f);
        float ltx = fmaxf(x1, bx1), lty = fmaxf(y1, by1);
        float rbx = fminf(x2, bx2), rby = fminf(y2, by2);
        float iw = fmaxf(rbx - ltx, 0.f), ih = fmaxf(rby - lty, 0.f);
        float inter = iw * ih;
        float iou = inter / (areai + areaj - inter + 1e-9f);
        if (iou > 0.7f) bits |= (1ULL << jj);
    }
    mask[(size_t)(n * KTOT + i) * MASK_STRIDE + blockIdx.y] = bits;
}

// ---------------- single-wave greedy NMS sweep per image ----------------
__global__ void k_nms(const float* __restrict__ ssc, const float* __restrict__ sbox,
                      const u64* __restrict__ mask, float* __restrict__ out) {
    int n = blockIdx.x, lane = threadIdx.x;
    __shared__ u64 rem[MASK_STRIDE];   // bit set = dead (invalid or suppressed)
    for (int c = 0; c < 79; ++c) {
        int i = c * 64 + lane;
        bool dead = (i >= KTOT) || !(ssc[n * KTOT + i] > -INFINITY);
        u64 db = __ballot(dead);
        if (lane == 0) rem[c] = db;
    }
    if (lane == 0) rem[79] = ~0ULL;
    __syncthreads();
    int picks = 0;
    for (int ch = 0; ch < 79 && picks < 1000; ++ch) {
        u64 rw = rem[ch];
        while (rw != ~0ULL && picks < 1000) {
            int j = __ffsll((u64)(~rw)) - 1;   // lowest alive bit
            int c = ch * 64 + j;
            if (lane == 0) {
                const float* bp = &sbox[(size_t)(n * KTOT + c) * 4];
                float* op = &out[(n * 1000 + picks) * 5];
                op[0] = bp[0]; op[1] = bp[1]; op[2] = bp[2]; op[3] = bp[3];
                op[4] = ssc[n * KTOT + c];
            }
            const u64* row = &mask[(size_t)(n * KTOT + c) * MASK_STRIDE];
            u64 v0 = row[lane];
            u64 v1 = (lane < 15) ? row[64 + lane] : 0ULL;
            if (ch < 64) { if (lane == ch) v0 |= (1ULL << j); }   // force self-dead
            else         { if (lane == ch - 64) v1 |= (1ULL << j); }
            rem[lane] |= v0;
            if (lane < 15) rem[64 + lane] |= v1;
            __syncthreads();
            rw = rem[ch];
            picks++;
        }
    }
    // zero-fill remaining output rows (reference emits zeros for invalid picks)
    int base = (n * 1000 + picks) * 5, cnt = (1000 - picks) * 5;
    for (int t = lane; t < cnt; t += 64) out[base + t] = 0.f;
}

// ---------------- workspace layout ----------------
constexpr size_t OFF_MASK   = 0;
constexpr size_t SZ_MASK    = (size_t)NIMG * KTOT * MASK_STRIDE * 8;   // 6,400,000
constexpr size_t OFF_HIST   = OFF_MASK + SZ_MASK;
constexpr size_t OFF_PREFIX = OFF_HIST + 10 * 256 * 4;
constexpr size_t OFF_KNEED  = OFF_PREFIX + 64;
constexpr size_t OFF_GCNT   = OFF_KNEED + 64;
constexpr size_t OFF_ECNT   = OFF_GCNT + 64;
constexpr size_t OFF_SEL    = OFF_ECNT + 64;
constexpr size_t OFF_EQ     = OFF_SEL + 10 * K_PER_LVL * 4;
constexpr size_t OFF_KEY64  = OFF_EQ + 10 * EQ_CAP * 4;                // 8-aligned
constexpr size_t OFF_CSC    = OFF_KEY64 + (size_t)NIMG * KTOT * 8;
constexpr size_t OFF_CBOX   = OFF_CSC + (size_t)NIMG * KTOT * 4;
constexpr size_t OFF_COBOX  = OFF_CBOX + (size_t)NIMG * KTOT * 16;
constexpr size_t OFF_SSC    = OFF_COBOX + (size_t)NIMG * KTOT * 16;
constexpr size_t OFF_SBOX   = OFF_SSC + (size_t)NIMG * KTOT * 4;
constexpr size_t OFF_SOBOX  = OFF_SBOX + (size_t)NIMG * KTOT * 16;
constexpr size_t WS_NEEDED  = OFF_SOBOX + (size_t)NIMG * KTOT * 16;    // ~7.33 MB

extern "C" void kernel_launch(void* const* d_in, const int* in_sizes, int n_in,
                              void* d_out, int out_size, void* d_ws, size_t ws_size,
                              hipStream_t stream) {
    if (ws_size < WS_NEEDED) return;

    // Detect input ordering from sizes: dict order interleaves (obj0,box0,...)
    // so in_sizes[1] (box0=6291456) > in_sizes[0] (obj0=1572864); signature
    // order (obj0..obj4,box0..box4) has in_sizes[1]=393216 < in_sizes[0].
    bool dictOrder = (in_sizes[1] > in_sizes[0]);
    Ptrs P;
    for (int l = 0; l < 5; ++l) {
        P.o[l] = (const float*)d_in[dictOrder ? (2 * l)     : l];
        P.b[l] = (const float*)d_in[dictOrder ? (2 * l + 1) : (5 + l)];
    }
    char* ws = (char*)d_ws;
    u64*   mask   = (u64*)(ws + OFF_MASK);
    u32*   hist   = (u32*)(ws + OFF_HIST);
    u32*   prefix = (u32*)(ws + OFF_PREFIX);
    int*   kneed  = (int*)(ws + OFF_KNEED);
    u32*   gcnt   = (u32*)(ws + OFF_GCNT);
    u32*   ecnt   = (u32*)(ws + OFF_ECNT);
    int*   sel    = (int*)(ws + OFF_SEL);
    int*   eq     = (int*)(ws + OFF_EQ);
    u64*   key64  = (u64*)(ws + OFF_KEY64);
    float* csc    = (float*)(ws + OFF_CSC);
    float* cbox   = (float*)(ws + OFF_CBOX);
    float* cobox  = (float*)(ws + OFF_COBOX);
    float* ssc    = (float*)(ws + OFF_SSC);
    float* sbox   = (float*)(ws + OFF_SBOX);
    float* sobox  = (float*)(ws + OFF_SOBOX);
    float* out    = (float*)d_out;

    k_init<<<1, 64, 0, stream>>>(hist, prefix, kneed, gcnt, ecnt);
    for (int pass = 0; pass < 4; ++pass) {
        k_hist<<<dim3(256, 10), 256, 0, stream>>>(P, hist, prefix, pass);
        k_resolve<<<1, 64, 0, stream>>>(hist, prefix, kneed, pass);
    }
    k_compact<<<dim3(256, 10), 256, 0, stream>>>(P, prefix, gcnt, ecnt, sel, eq);
    k_eqsel<<<10, 64, 0, stream>>>(ecnt, kneed, eq, sel);
    k_feat<<<dim3((NIMG * KTOT + 255) / 256), 256, 0, stream>>>(P, sel, key64, csc, cbox, cobox);
    k_rank<<<dim3((KTOT + 255) / 256, NIMG), 256, 0, stream>>>(key64, csc, cbox, cobox, ssc, sbox, sobox);
    k_mask<<<dim3(79, 79, NIMG), 64, 0, stream>>>(sobox, mask);
    k_nms<<<NIMG, 64, 0, stream>>>(ssc, sbox, mask, out);
}

// Round 3
// 722.150 us; speedup vs baseline: 1.3544x; 1.3544x over previous
//
#include <hip/hip_runtime.h>
#include <cmath>

#pragma clang fp contract(off)

typedef unsigned int u32;
typedef unsigned long long u64;

#define K_PER_LVL 1000
#define KTOT 5000            // 5 levels * 1000
#define NIMG 2
#define MASK_STRIDE 80       // u64 words per mask row (79 used, 1 pad)
#define EQ_CAP 256
#define SPEC_D 16            // NMS speculation depth

__constant__ int c_LG[5] = {512, 256, 128, 64, 32};      // grid dim (square)
__constant__ int c_LS[5] = {4, 8, 16, 32, 64};           // stride
__constant__ int c_LZ[5] = {32, 64, 128, 256, 512};      // anchor size
__constant__ int c_LM[5] = {786432, 196608, 49152, 12288, 3072}; // 3*G*G

struct Ptrs { const float* o[5]; const float* b[5]; };

// monotone float -> uint key (larger float => larger key)
__device__ inline u32 fkey(float f) {
    u32 u = __float_as_uint(f);
    return (u & 0x80000000u) ? ~u : (u | 0x80000000u);
}

// ---------------- init ----------------
__global__ void k_init(u32* hist, u32* prefix, int* kneed, u32* gcnt, u32* ecnt) {
    int t = threadIdx.x;
    for (int i = t; i < 2560; i += 64) hist[i] = 0;
    if (t < 10) { prefix[t] = 0; kneed[t] = K_PER_LVL; gcnt[t] = 0; ecnt[t] = 0; }
}

// ---------------- radix-select histogram pass ----------------
__global__ void k_hist(Ptrs P, u32* __restrict__ hist, const u32* __restrict__ prefix, int pass) {
    int p = blockIdx.y; int l = p % 5; int n = p / 5;
    int M = c_LM[l];
    const float* base = P.o[l] + (size_t)n * M;
    __shared__ u32 lh[256];
    lh[threadIdx.x] = 0;
    __syncthreads();
    int shift = 24 - 8 * pass;
    int hi = (pass == 0) ? 31 : (shift + 8);
    u32 pref = prefix[p];
    int stride = gridDim.x * 256;
    for (int i = blockIdx.x * 256 + threadIdx.x; i < M; i += stride) {
        u32 k = fkey(base[i]);
        bool ok = (pass == 0) || ((k >> hi) == (pref >> hi));
        if (ok) atomicAdd(&lh[(k >> shift) & 255], 1u);
    }
    __syncthreads();
    u32 c = lh[threadIdx.x];
    if (c) atomicAdd(&hist[p * 256 + threadIdx.x], c);
}

// ---------------- radix-select resolve ----------------
__global__ void k_resolve(u32* hist, u32* prefix, int* kneed, int pass) {
    int t = threadIdx.x;
    if (t < 10) {
        int K = kneed[t];
        u32 G = 0; int B = 0;
        for (int b = 255; b >= 0; --b) {
            u32 c = hist[t * 256 + b];
            if (G + c >= (u32)K) { B = b; break; }
            G += c;
        }
        int shift = 24 - 8 * pass;
        prefix[t] |= ((u32)B) << shift;
        kneed[t] = K - (int)G;
    }
    __syncthreads();
    if (pass < 3) {
        for (int i = t; i < 2560; i += 64) hist[i] = 0;
    }
}

// ---------------- compact: >T -> sel front; ==T -> eq buffer ----------------
__global__ void k_compact(Ptrs P, const u32* __restrict__ prefix,
                          u32* gcnt, u32* ecnt, int* __restrict__ sel, int* __restrict__ eq) {
    int p = blockIdx.y; int l = p % 5; int n = p / 5;
    int M = c_LM[l]; int gg = M / 3;
    const float* base = P.o[l] + (size_t)n * M;
    u32 T = prefix[p];
    int stride = gridDim.x * 256;
    for (int i = blockIdx.x * 256 + threadIdx.x; i < M; i += stride) {
        u32 k = fkey(base[i]);
        if (k < T) continue;
        // input linear i = a*gg + pix ; flattened m = pix*3 + a  (h,w,a order)
        int a = i / gg; int pix = i - a * gg; int m = pix * 3 + a;
        if (k > T) {
            u32 pos = atomicAdd(&gcnt[p], 1u);
            sel[p * K_PER_LVL + pos] = m;
        } else {
            u32 e = atomicAdd(&ecnt[p], 1u);
            if (e < EQ_CAP) eq[p * EQ_CAP + e] = m;
        }
    }
}

// ---------------- boundary ties: pick KF lowest flat-indices (top_k tie rule) ----------------
__global__ void k_eqsel(const u32* __restrict__ ecnt, const int* __restrict__ kneed,
                        int* eq, int* __restrict__ sel) {
    int p = blockIdx.x;
    if (threadIdx.x != 0) return;
    int E = (int)ecnt[p]; if (E > EQ_CAP) E = EQ_CAP;
    int KF = kneed[p];
    int G0 = K_PER_LVL - KF;
    int* e = eq + p * EQ_CAP;
    for (int r = 0; r < KF && r < E; ++r) {       // partial selection sort, ascending m
        int mi = r;
        for (int q = r + 1; q < E; ++q) if (e[q] < e[mi]) mi = q;
        int t = e[mi]; e[mi] = e[r]; e[r] = t;
        sel[p * K_PER_LVL + G0 + r] = t;
    }
}

// ---------------- featurize: anchors + decode + clip + score + 64b order key ----------------
__global__ void k_feat(Ptrs P, const int* __restrict__ sel, u64* __restrict__ key64,
                       float* __restrict__ csc, float* __restrict__ cbox, float* __restrict__ cobox) {
    int tid = blockIdx.x * 256 + threadIdx.x;
    if (tid >= NIMG * KTOT) return;
    int p = tid / K_PER_LVL, s = tid - p * K_PER_LVL;
    int n = p / 5, l = p % 5;
    int G = c_LG[l], S = c_LS[l], Z = c_LZ[l];
    int gg = G * G;
    int m = sel[p * K_PER_LVL + s];
    int a = m % 3; int pix = m / 3; int h = pix / G; int w = pix - h * G;

    // anchor base: hr=sqrt(ar), wr=1/hr, round-half-even (matches jnp f32)
    const float ars[3] = {0.5f, 1.0f, 2.0f};
    float ar = ars[a];
    float hr = sqrtf(ar), wr = 1.0f / hr;
    float wsz = wr * (float)Z, hsz = hr * (float)Z;
    float bx1 = rintf(-0.5f * wsz), by1 = rintf(-0.5f * hsz);
    float bx2 = rintf(0.5f * wsz),  by2 = rintf(0.5f * hsz);
    float sx = (float)(w * S), sy = (float)(h * S);
    float ax1 = sx + bx1, ay1 = sy + by1, ax2 = sx + bx2, ay2 = sy + by2;
    float wa = ax2 - ax1, ha = ay2 - ay1;
    float cxa = ax1 + 0.5f * wa, cya = ay1 + 0.5f * ha;

    const float* bb = P.b[l] + (size_t)n * 12 * gg;
    float dx = bb[(a * 4 + 0) * gg + pix];
    float dy = bb[(a * 4 + 1) * gg + pix];
    const float CLIPV = 4.135166556742356f;  // log(1000/16)
    float dw = fminf(bb[(a * 4 + 2) * gg + pix], CLIPV);
    float dh = fminf(bb[(a * 4 + 3) * gg + pix], CLIPV);
    float cx = dx * wa + cxa, cy = dy * ha + cya;
    float ww = expf(dw) * wa, hh = expf(dh) * ha;
    float x1 = cx - 0.5f * ww, y1 = cy - 0.5f * hh;
    float x2 = cx + 0.5f * ww, y2 = cy + 0.5f * hh;
    x1 = fminf(fmaxf(x1, 0.f), 2048.f);
    y1 = fminf(fmaxf(y1, 0.f), 2048.f);
    x2 = fminf(fmaxf(x2, 0.f), 2048.f);
    y2 = fminf(fmaxf(y2, 0.f), 2048.f);

    float raw = P.o[l][(size_t)n * 3 * gg + a * gg + pix];
    float sc = 1.0f / (1.0f + expf(-raw));
    bool keep = (x2 - x1 >= 1e-3f) && (y2 - y1 >= 1e-3f) && (sc > 0.0f);

    int slot = n * KTOT + l * K_PER_LVL + s;
    // total order key: raw desc, then (level asc, m asc) == reference concat-position order
    u32 tb = ((u32)l << 20) | (u32)m;          // m < 2^20, l < 8  -> 23 bits, unique
    u32 kk = keep ? fkey(raw) : 0u;            // invalid sinks below every valid (finite raw)
    key64[slot] = ((u64)kk << 23) | (u64)(tb ^ 0x7FFFFFu);

    csc[slot] = keep ? sc : -INFINITY;
    cbox[slot * 4 + 0] = x1; cbox[slot * 4 + 1] = y1;
    cbox[slot * 4 + 2] = x2; cbox[slot * 4 + 3] = y2;
    float off = 4097.0f * (float)l;            // lvl * (W+H+1), batched_nms offset
    cobox[slot * 4 + 0] = x1 + off; cobox[slot * 4 + 1] = y1 + off;
    cobox[slot * 4 + 2] = x2 + off; cobox[slot * 4 + 3] = y2 + off;
}

// ---------------- exact rank by counting (keys unique -> permutation), scatter ----------------
__global__ void k_rank(const u64* __restrict__ key64, const float* __restrict__ csc,
                       const float* __restrict__ cbox, const float* __restrict__ cobox,
                       float* __restrict__ ssc, float* __restrict__ sbox, float* __restrict__ sobox) {
    int n = blockIdx.y;
    int i = blockIdx.x * 256 + threadIdx.x;
    if (i >= KTOT) return;
    const u64* kb = key64 + (size_t)n * KTOT;
    u64 ki = kb[i];
    int rank = 0;
    for (int j = 0; j < KTOT; ++j) rank += (kb[j] > ki) ? 1 : 0;
    int src = n * KTOT + i, dst = n * KTOT + rank;
    ssc[dst] = csc[src];
    sbox[dst * 4 + 0] = cbox[src * 4 + 0]; sbox[dst * 4 + 1] = cbox[src * 4 + 1];
    sbox[dst * 4 + 2] = cbox[src * 4 + 2]; sbox[dst * 4 + 3] = cbox[src * 4 + 3];
    sobox[dst * 4 + 0] = cobox[src * 4 + 0]; sobox[dst * 4 + 1] = cobox[src * 4 + 1];
    sobox[dst * 4 + 2] = cobox[src * 4 + 2]; sobox[dst * 4 + 3] = cobox[src * 4 + 3];
}

// ---------------- IoU suppression bitmask matrix ----------------
__global__ void k_mask(const float* __restrict__ sobox, u64* __restrict__ mask) {
    int n = blockIdx.z;
    int i = blockIdx.x * 64 + threadIdx.x;
    int j0 = blockIdx.y * 64;
    __shared__ float cb[64][4];
    int jl = j0 + threadIdx.x;
    if (jl < KTOT) {
        cb[threadIdx.x][0] = sobox[(size_t)(n * KTOT + jl) * 4 + 0];
        cb[threadIdx.x][1] = sobox[(size_t)(n * KTOT + jl) * 4 + 1];
        cb[threadIdx.x][2] = sobox[(size_t)(n * KTOT + jl) * 4 + 2];
        cb[threadIdx.x][3] = sobox[(size_t)(n * KTOT + jl) * 4 + 3];
    } else {
        cb[threadIdx.x][0] = 0.f; cb[threadIdx.x][1] = 0.f;
        cb[threadIdx.x][2] = 0.f; cb[threadIdx.x][3] = 0.f;
    }
    __syncthreads();
    if (i >= KTOT) return;
    float x1 = sobox[(size_t)(n * KTOT + i) * 4 + 0];
    float y1 = sobox[(size_t)(n * KTOT + i) * 4 + 1];
    float x2 = sobox[(size_t)(n * KTOT + i) * 4 + 2];
    float y2 = sobox[(size_t)(n * KTOT + i) * 4 + 3];
    float areai = fmaxf(x2 - x1, 0.f) * fmaxf(y2 - y1, 0.f);
    u64 bits = 0;
    int lim = KTOT - j0; if (lim > 64) lim = 64;
    for (int jj = 0; jj < lim; ++jj) {
        float bx1 = cb[jj][0], by1 = cb[jj][1], bx2 = cb[jj][2], by2 = cb[jj][3];
        float areaj = fmaxf(bx2 - bx1, 0.f) * fmaxf(by2 - by1, 0.f);
        float ltx = fmaxf(x1, bx1), lty = fmaxf(y1, by1);
        float rbx = fminf(x2, bx2), rby = fminf(y2, by2);
        float iw = fmaxf(rbx - ltx, 0.f), ih = fmaxf(rby - lty, 0.f);
        float inter = iw * ih;
        float iou = inter / (areai + areaj - inter + 1e-9f);
        if (iou > 0.7f) bits |= (1ULL << jj);
    }
    mask[(size_t)(n * KTOT + i) * MASK_STRIDE + blockIdx.y] = bits;
}

// ---------------- speculative single-wave greedy NMS sweep per image ----------------
// Exact greedy semantics: candidates are rank-sorted; each batch takes the
// SPEC_D lowest alive candidates from the current dead-map, loads all their
// suppression rows in ONE memory latency, then commits them in ascending
// order with an in-register validity check (a pick is skipped iff an earlier
// commit in the same batch suppresses it — identical to serial greedy).
__global__ void k_nms(const float* __restrict__ ssc, const float* __restrict__ sbox,
                      const u64* __restrict__ mask, float* __restrict__ out) {
    int n = blockIdx.x, lane = threadIdx.x;
    __shared__ u64 rem[MASK_STRIDE];   // bit set = dead (invalid or suppressed)
    __shared__ int lst[SPEC_D];
    for (int c = 0; c < 79; ++c) {
        int i = c * 64 + lane;
        bool dead = (i >= KTOT) || !(ssc[n * KTOT + i] > -INFINITY);
        u64 db = __ballot(dead);
        if (lane == 0) rem[c] = db;
    }
    if (lane == 0) rem[79] = ~0ULL;
    __syncthreads();

    int picks = 0;
    int cur = 0;   // all words < cur are fully dead (monotone)
    while (picks < 1000 && cur < 79) {
        // ---- scan 64-word window for the SPEC_D lowest alive candidates ----
        int wi = cur + lane;
        u64 alive = (wi < 79) ? ~rem[wi] : 0ULL;
        int pc = __popcll(alive);
        int inc = pc;
        #pragma unroll
        for (int off = 1; off < 64; off <<= 1) {
            int v = __shfl_up(inc, off);
            if (lane >= off) inc += v;
        }
        int tot = __shfl(inc, 63);
        if (tot == 0) { cur += 64; continue; }
        int excl = inc - pc;
        {
            u64 a = alive; int r = excl;
            while (a && r < SPEC_D) {
                int b = __ffsll(a) - 1;
                lst[r] = wi * 64 + b;
                a &= a - 1; r++;
            }
        }
        int batchN = tot < SPEC_D ? tot : SPEC_D;
        __syncthreads();

        // ---- parallel row loads (all independent -> one latency) ----
        u64 r0[SPEC_D], r1[SPEC_D];
        int c0 = lst[0];
        #pragma unroll
        for (int d = 0; d < SPEC_D; ++d) {
            int c = (d < batchN) ? lst[d] : c0;
            const u64* row = &mask[(size_t)(n * KTOT + c) * MASK_STRIDE];
            r0[d] = row[lane];
            r1[d] = (lane < 15) ? row[64 + lane] : 0ULL;
        }
        // box/score prefetch: lane d holds candidate d's output payload
        float bv0 = 0.f, bv1 = 0.f, bv2 = 0.f, bv3 = 0.f, bvs = 0.f;
        if (lane < batchN) {
            int c = lst[lane];
            const float* bp = &sbox[(size_t)(n * KTOT + c) * 4];
            bv0 = bp[0]; bv1 = bp[1]; bv2 = bp[2]; bv3 = bp[3];
            bvs = ssc[n * KTOT + c];
        }

        // ---- sequential commit with in-register batch suppression ----
        u64 supp0 = 0, supp1 = 0;
        u32 cm = 0;
        int base = picks;
        #pragma unroll
        for (int d = 0; d < SPEC_D; ++d) {
            if (d < batchN && picks < 1000) {
                int c = lst[d]; int w = c >> 6, b = c & 63;
                bool deadp = (w < 64) ? ((lane == w) && ((supp0 >> b) & 1))
                                      : ((lane == (w - 64)) && ((supp1 >> b) & 1));
                if (__ballot(deadp) == 0ULL) {
                    supp0 |= r0[d];
                    if (lane < 15) supp1 |= r1[d];
                    cm |= (1u << d);
                    picks++;
                }
            }
        }
        // stores (off the critical chain)
        if (lane < batchN && ((cm >> lane) & 1u)) {
            int pos = base + __popc(cm & ((1u << lane) - 1u));
            float* op = &out[(n * 1000 + pos) * 5];
            op[0] = bv0; op[1] = bv1; op[2] = bv2; op[3] = bv3; op[4] = bvs;
        }
        // ---- apply to dead-map, advance cursor ----
        rem[lane] |= supp0;
        if (lane < 15) rem[64 + lane] |= supp1;
        __syncthreads();
        u64 winAlive = ((cur + lane) < 79) ? ~rem[cur + lane] : 0ULL;
        u64 bal = __ballot(winAlive != 0ULL);
        if (bal == 0ULL) cur += 64;
        else cur += __ffsll(bal) - 1;
        __syncthreads();
    }
    // zero-fill remaining output rows (reference emits zeros for invalid picks)
    int basec = (n * 1000 + picks) * 5, cnt = (1000 - picks) * 5;
    for (int t = lane; t < cnt; t += 64) out[basec + t] = 0.f;
}

// ---------------- workspace layout ----------------
constexpr size_t OFF_MASK   = 0;
constexpr size_t SZ_MASK    = (size_t)NIMG * KTOT * MASK_STRIDE * 8;   // 6,400,000
constexpr size_t OFF_HIST   = OFF_MASK + SZ_MASK;
constexpr size_t OFF_PREFIX = OFF_HIST + 10 * 256 * 4;
constexpr size_t OFF_KNEED  = OFF_PREFIX + 64;
constexpr size_t OFF_GCNT   = OFF_KNEED + 64;
constexpr size_t OFF_ECNT   = OFF_GCNT + 64;
constexpr size_t OFF_SEL    = OFF_ECNT + 64;
constexpr size_t OFF_EQ     = OFF_SEL + 10 * K_PER_LVL * 4;
constexpr size_t OFF_KEY64  = OFF_EQ + 10 * EQ_CAP * 4;                // 8-aligned
constexpr size_t OFF_CSC    = OFF_KEY64 + (size_t)NIMG * KTOT * 8;
constexpr size_t OFF_CBOX   = OFF_CSC + (size_t)NIMG * KTOT * 4;
constexpr size_t OFF_COBOX  = OFF_CBOX + (size_t)NIMG * KTOT * 16;
constexpr size_t OFF_SSC    = OFF_COBOX + (size_t)NIMG * KTOT * 16;
constexpr size_t OFF_SBOX   = OFF_SSC + (size_t)NIMG * KTOT * 4;
constexpr size_t OFF_SOBOX  = OFF_SBOX + (size_t)NIMG * KTOT * 16;
constexpr size_t WS_NEEDED  = OFF_SOBOX + (size_t)NIMG * KTOT * 16;    // ~7.33 MB

extern "C" void kernel_launch(void* const* d_in, const int* in_sizes, int n_in,
                              void* d_out, int out_size, void* d_ws, size_t ws_size,
                              hipStream_t stream) {
    if (ws_size < WS_NEEDED) return;

    // Detect input ordering from sizes: dict order interleaves (obj0,box0,...)
    // so in_sizes[1] (box0=6291456) > in_sizes[0] (obj0=1572864); signature
    // order (obj0..obj4,box0..box4) has in_sizes[1]=393216 < in_sizes[0].
    bool dictOrder = (in_sizes[1] > in_sizes[0]);
    Ptrs P;
    for (int l = 0; l < 5; ++l) {
        P.o[l] = (const float*)d_in[dictOrder ? (2 * l)     : l];
        P.b[l] = (const float*)d_in[dictOrder ? (2 * l + 1) : (5 + l)];
    }
    char* ws = (char*)d_ws;
    u64*   mask   = (u64*)(ws + OFF_MASK);
    u32*   hist   = (u32*)(ws + OFF_HIST);
    u32*   prefix = (u32*)(ws + OFF_PREFIX);
    int*   kneed  = (int*)(ws + OFF_KNEED);
    u32*   gcnt   = (u32*)(ws + OFF_GCNT);
    u32*   ecnt   = (u32*)(ws + OFF_ECNT);
    int*   sel    = (int*)(ws + OFF_SEL);
    int*   eq     = (int*)(ws + OFF_EQ);
    u64*   key64  = (u64*)(ws + OFF_KEY64);
    float* csc    = (float*)(ws + OFF_CSC);
    float* cbox   = (float*)(ws + OFF_CBOX);
    float* cobox  = (float*)(ws + OFF_COBOX);
    float* ssc    = (float*)(ws + OFF_SSC);
    float* sbox   = (float*)(ws + OFF_SBOX);
    float* sobox  = (float*)(ws + OFF_SOBOX);
    float* out    = (float*)d_out;

    k_init<<<1, 64, 0, stream>>>(hist, prefix, kneed, gcnt, ecnt);
    for (int pass = 0; pass < 4; ++pass) {
        k_hist<<<dim3(256, 10), 256, 0, stream>>>(P, hist, prefix, pass);
        k_resolve<<<1, 64, 0, stream>>>(hist, prefix, kneed, pass);
    }
    k_compact<<<dim3(256, 10), 256, 0, stream>>>(P, prefix, gcnt, ecnt, sel, eq);
    k_eqsel<<<10, 64, 0, stream>>>(ecnt, kneed, eq, sel);
    k_feat<<<dim3((NIMG * KTOT + 255) / 256), 256, 0, stream>>>(P, sel, key64, csc, cbox, cobox);
    k_rank<<<dim3((KTOT + 255) / 256, NIMG), 256, 0, stream>>>(key64, csc, cbox, cobox, ssc, sbox, sobox);
    k_mask<<<dim3(79, 79, NIMG), 64, 0, stream>>>(sobox, mask);
    k_nms<<<NIMG, 64, 0, stream>>>(ssc, sbox, mask, out);
}

// Round 5
// 654.463 us; speedup vs baseline: 1.4945x; 1.1034x over previous
//
#include <hip/hip_runtime.h>
#include <cmath>

#pragma clang fp contract(off)

typedef unsigned int u32;
typedef unsigned long long u64;

#define K_PER_LVL 1000
#define KTOT 5000            // 5 levels * 1000
#define NIMG 2
#define MASK_STRIDE 80       // u64 words per mask row (79 used, 1 pad)
#define BINS 2048            // histogram bins = top 11 bits of fkey
#define BIN_SHIFT 21
#define EQ_CAP 2048
#define SPEC_D 24            // NMS speculation depth

__constant__ int c_LG[5] = {512, 256, 128, 64, 32};      // grid dim (square)
__constant__ int c_LS[5] = {4, 8, 16, 32, 64};           // stride
__constant__ int c_LZ[5] = {32, 64, 128, 256, 512};      // anchor size
__constant__ int c_LM[5] = {786432, 196608, 49152, 12288, 3072}; // 3*G*G

struct Ptrs { const float* o[5]; const float* b[5]; };

// monotone float -> uint key (larger float => larger key)
__device__ inline u32 fkey(float f) {
    u32 u = __float_as_uint(f);
    return (u & 0x80000000u) ? ~u : (u | 0x80000000u);
}

// ---------------- zero hist + counters (replaces hipMemsetAsync: zero host-API in capture) ----------------
__global__ __launch_bounds__(256) void k_zero(u32* __restrict__ z, int nwords) {
    int i = blockIdx.x * 256 + threadIdx.x;
    int stride = gridDim.x * 256;
    for (; i < nwords; i += stride) z[i] = 0;
}

// ---------------- one-pass 2048-bin histogram (float4 loads, LDS pre-agg) ----------------
__global__ __launch_bounds__(256) void k_hist(Ptrs P, u32* __restrict__ hist) {
    int p = blockIdx.y; int l = p % 5; int n = p / 5;
    int M4 = c_LM[l] >> 2;
    const float4* base = (const float4*)(P.o[l] + (size_t)n * c_LM[l]);
    __shared__ u32 lh[BINS];
    for (int i = threadIdx.x; i < BINS; i += 256) lh[i] = 0;
    __syncthreads();
    int stride = gridDim.x * 256;
    for (int i = blockIdx.x * 256 + threadIdx.x; i < M4; i += stride) {
        float4 v = base[i];
        atomicAdd(&lh[fkey(v.x) >> BIN_SHIFT], 1u);
        atomicAdd(&lh[fkey(v.y) >> BIN_SHIFT], 1u);
        atomicAdd(&lh[fkey(v.z) >> BIN_SHIFT], 1u);
        atomicAdd(&lh[fkey(v.w) >> BIN_SHIFT], 1u);
    }
    __syncthreads();
    for (int i = threadIdx.x; i < BINS; i += 256) {
        u32 c = lh[i];
        if (c) atomicAdd(&hist[p * BINS + i], c);
    }
}

// ---------------- resolve: find threshold bin B, G = #(keys in bins > B), KF = 1000 - G ----------------
__global__ __launch_bounds__(256) void k_resolve(const u32* __restrict__ hist,
                                                 int* __restrict__ binB, int* __restrict__ kneed,
                                                 int* __restrict__ g0) {
    int p = blockIdx.x, t = threadIdx.x;
    __shared__ u32 lh[BINS];
    __shared__ u32 seg[256];
    for (int i = t; i < BINS; i += 256) lh[i] = hist[p * BINS + i];
    __syncthreads();
    u32 s = 0;
    for (int q = 0; q < 8; ++q) s += lh[t * 8 + q];
    seg[t] = s;
    __syncthreads();
    if (t == 0) {
        u32 G = 0; int B = 0;
        for (int sg = 255; sg >= 0; --sg) {
            if (G + seg[sg] >= (u32)K_PER_LVL) {
                for (int b = sg * 8 + 7; b >= sg * 8; --b) {
                    u32 c = lh[b];
                    if (G + c >= (u32)K_PER_LVL) { B = b; break; }
                    G += c;
                }
                break;
            }
            G += seg[sg];
        }
        binB[p] = B;
        kneed[p] = K_PER_LVL - (int)G;   // KF taken from boundary bin
        g0[p] = (int)G;                  // count strictly above bin B
    }
}

// ---------------- compact: bin>B -> sel front; bin==B -> eq (packed key|~m) ----------------
__global__ __launch_bounds__(256) void k_compact(Ptrs P, const int* __restrict__ binB,
                                                 u32* gcnt, u32* ecnt,
                                                 int* __restrict__ sel, u64* __restrict__ eq) {
    int p = blockIdx.y; int l = p % 5; int n = p / 5;
    int M4 = c_LM[l] >> 2; int gg = c_LM[l] / 3;
    const float4* base = (const float4*)(P.o[l] + (size_t)n * c_LM[l]);
    int B = binB[p];
    int stride = gridDim.x * 256;
    for (int i4 = blockIdx.x * 256 + threadIdx.x; i4 < M4; i4 += stride) {
        float4 v = base[i4];
        float vv[4] = {v.x, v.y, v.z, v.w};
        #pragma unroll
        for (int q = 0; q < 4; ++q) {
            u32 k = fkey(vv[q]);
            int bin = (int)(k >> BIN_SHIFT);
            if (bin < B) continue;
            int i = i4 * 4 + q;
            // input linear i = a*gg + pix ; flattened m = pix*3 + a  (h,w,a order)
            int a = i / gg; int pix = i - a * gg; int m = pix * 3 + a;
            if (bin > B) {
                u32 pos = atomicAdd(&gcnt[p], 1u);
                sel[p * K_PER_LVL + pos] = m;
            } else {
                u32 e = atomicAdd(&ecnt[p], 1u);
                if (e < EQ_CAP) eq[(size_t)p * EQ_CAP + e] = ((u64)k << 20) | (u64)(0xFFFFFu ^ (u32)m);
            }
        }
    }
}

// ---------------- boundary bin: exact order (key desc, m asc) via LDS bitonic, take KF ----------------
__global__ __launch_bounds__(256) void k_eqsel(const u32* __restrict__ ecnt, const int* __restrict__ kneed,
                                               const int* __restrict__ g0,
                                               const u64* __restrict__ eq, int* __restrict__ sel) {
    int p = blockIdx.x, t = threadIdx.x;
    int E = (int)ecnt[p]; if (E > EQ_CAP) E = EQ_CAP;
    int KF = kneed[p]; int G0 = g0[p];
    __shared__ u64 a[EQ_CAP];
    for (int i = t; i < EQ_CAP; i += 256) a[i] = (i < E) ? eq[(size_t)p * EQ_CAP + i] : 0ULL;
    __syncthreads();
    for (int k = 2; k <= EQ_CAP; k <<= 1) {
        for (int j = k >> 1; j > 0; j >>= 1) {
            for (int i = t; i < EQ_CAP; i += 256) {
                int x = i ^ j;
                if (x > i) {
                    u64 va = a[i], vb = a[x];
                    bool up = (i & k) == 0;                 // descending sort
                    bool sw = up ? (va < vb) : (va > vb);
                    if (sw) { a[i] = vb; a[x] = va; }
                }
            }
            __syncthreads();
        }
    }
    for (int r = t; r < KF; r += 256) {
        int m = (int)(0xFFFFFu ^ (u32)(a[r] & 0xFFFFFu));
        sel[p * K_PER_LVL + G0 + r] = m;
    }
}

// ---------------- featurize: anchors + decode + clip + score + 64b order key ----------------
__global__ void k_feat(Ptrs P, const int* __restrict__ sel, u64* __restrict__ key64,
                       float* __restrict__ csc, float* __restrict__ cbox, float* __restrict__ cobox) {
    int tid = blockIdx.x * 256 + threadIdx.x;
    if (tid >= NIMG * KTOT) return;
    int p = tid / K_PER_LVL, s = tid - p * K_PER_LVL;
    int n = p / 5, l = p % 5;
    int G = c_LG[l], S = c_LS[l], Z = c_LZ[l];
    int gg = G * G;
    int m = sel[p * K_PER_LVL + s];
    int a = m % 3; int pix = m / 3; int h = pix / G; int w = pix - h * G;

    // anchor base: hr=sqrt(ar), wr=1/hr, round-half-even (matches jnp f32)
    const float ars[3] = {0.5f, 1.0f, 2.0f};
    float ar = ars[a];
    float hr = sqrtf(ar), wr = 1.0f / hr;
    float wsz = wr * (float)Z, hsz = hr * (float)Z;
    float bx1 = rintf(-0.5f * wsz), by1 = rintf(-0.5f * hsz);
    float bx2 = rintf(0.5f * wsz),  by2 = rintf(0.5f * hsz);
    float sx = (float)(w * S), sy = (float)(h * S);
    float ax1 = sx + bx1, ay1 = sy + by1, ax2 = sx + bx2, ay2 = sy + by2;
    float wa = ax2 - ax1, ha = ay2 - ay1;
    float cxa = ax1 + 0.5f * wa, cya = ay1 + 0.5f * ha;

    const float* bb = P.b[l] + (size_t)n * 12 * gg;
    float dx = bb[(a * 4 + 0) * gg + pix];
    float dy = bb[(a * 4 + 1) * gg + pix];
    const float CLIPV = 4.135166556742356f;  // log(1000/16)
    float dw = fminf(bb[(a * 4 + 2) * gg + pix], CLIPV);
    float dh = fminf(bb[(a * 4 + 3) * gg + pix], CLIPV);
    float cx = dx * wa + cxa, cy = dy * ha + cya;
    float ww = expf(dw) * wa, hh = expf(dh) * ha;
    float x1 = cx - 0.5f * ww, y1 = cy - 0.5f * hh;
    float x2 = cx + 0.5f * ww, y2 = cy + 0.5f * hh;
    x1 = fminf(fmaxf(x1, 0.f), 2048.f);
    y1 = fminf(fmaxf(y1, 0.f), 2048.f);
    x2 = fminf(fmaxf(x2, 0.f), 2048.f);
    y2 = fminf(fmaxf(y2, 0.f), 2048.f);

    float raw = P.o[l][(size_t)n * 3 * gg + a * gg + pix];
    float sc = 1.0f / (1.0f + expf(-raw));
    bool keep = (x2 - x1 >= 1e-3f) && (y2 - y1 >= 1e-3f) && (sc > 0.0f);

    int slot = n * KTOT + l * K_PER_LVL + s;
    // total order key: raw desc, then (level asc, m asc) == reference concat-position order
    u32 tb = ((u32)l << 20) | (u32)m;          // m < 2^20, l < 8  -> 23 bits, unique
    u32 kk = keep ? fkey(raw) : 0u;            // invalid sinks below every valid (finite raw)
    key64[slot] = ((u64)kk << 23) | (u64)(tb ^ 0x7FFFFFu);

    csc[slot] = keep ? sc : -INFINITY;
    cbox[slot * 4 + 0] = x1; cbox[slot * 4 + 1] = y1;
    cbox[slot * 4 + 2] = x2; cbox[slot * 4 + 3] = y2;
    float off = 4097.0f * (float)l;            // lvl * (W+H+1), batched_nms offset
    cobox[slot * 4 + 0] = x1 + off; cobox[slot * 4 + 1] = y1 + off;
    cobox[slot * 4 + 2] = x2 + off; cobox[slot * 4 + 3] = y2 + off;
}

// ---------------- exact rank by counting (keys unique -> permutation), scatter ----------------
__global__ void k_rank(const u64* __restrict__ key64, const float* __restrict__ csc,
                       const float* __restrict__ cbox, const float* __restrict__ cobox,
                       float* __restrict__ ssc, float* __restrict__ sbox, float* __restrict__ sobox) {
    int n = blockIdx.y;
    int i = blockIdx.x * 256 + threadIdx.x;
    if (i >= KTOT) return;
    const u64* kb = key64 + (size_t)n * KTOT;
    u64 ki = kb[i];
    int rank = 0;
    for (int j = 0; j < KTOT; ++j) rank += (kb[j] > ki) ? 1 : 0;
    int src = n * KTOT + i, dst = n * KTOT + rank;
    ssc[dst] = csc[src];
    sbox[dst * 4 + 0] = cbox[src * 4 + 0]; sbox[dst * 4 + 1] = cbox[src * 4 + 1];
    sbox[dst * 4 + 2] = cbox[src * 4 + 2]; sbox[dst * 4 + 3] = cbox[src * 4 + 3];
    sobox[dst * 4 + 0] = cobox[src * 4 + 0]; sobox[dst * 4 + 1] = cobox[src * 4 + 1];
    sobox[dst * 4 + 2] = cobox[src * 4 + 2]; sobox[dst * 4 + 3] = cobox[src * 4 + 3];
}

// ---------------- IoU suppression bitmask matrix ----------------
__global__ void k_mask(const float* __restrict__ sobox, u64* __restrict__ mask) {
    int n = blockIdx.z;
    int i = blockIdx.x * 64 + threadIdx.x;
    int j0 = blockIdx.y * 64;
    __shared__ float cb[64][4];
    int jl = j0 + threadIdx.x;
    if (jl < KTOT) {
        cb[threadIdx.x][0] = sobox[(size_t)(n * KTOT + jl) * 4 + 0];
        cb[threadIdx.x][1] = sobox[(size_t)(n * KTOT + jl) * 4 + 1];
        cb[threadIdx.x][2] = sobox[(size_t)(n * KTOT + jl) * 4 + 2];
        cb[threadIdx.x][3] = sobox[(size_t)(n * KTOT + jl) * 4 + 3];
    } else {
        cb[threadIdx.x][0] = 0.f; cb[threadIdx.x][1] = 0.f;
        cb[threadIdx.x][2] = 0.f; cb[threadIdx.x][3] = 0.f;
    }
    __syncthreads();
    if (i >= KTOT) return;
    float x1 = sobox[(size_t)(n * KTOT + i) * 4 + 0];
    float y1 = sobox[(size_t)(n * KTOT + i) * 4 + 1];
    float x2 = sobox[(size_t)(n * KTOT + i) * 4 + 2];
    float y2 = sobox[(size_t)(n * KTOT + i) * 4 + 3];
    float areai = fmaxf(x2 - x1, 0.f) * fmaxf(y2 - y1, 0.f);
    u64 bits = 0;
    int lim = KTOT - j0; if (lim > 64) lim = 64;
    for (int jj = 0; jj < lim; ++jj) {
        float bx1 = cb[jj][0], by1 = cb[jj][1], bx2 = cb[jj][2], by2 = cb[jj][3];
        float areaj = fmaxf(bx2 - bx1, 0.f) * fmaxf(by2 - by1, 0.f);
        float ltx = fmaxf(x1, bx1), lty = fmaxf(y1, by1);
        float rbx = fminf(x2, bx2), rby = fminf(y2, by2);
        float iw = fmaxf(rbx - ltx, 0.f), ih = fmaxf(rby - lty, 0.f);
        float inter = iw * ih;
        float iou = inter / (areai + areaj - inter + 1e-9f);
        if (iou > 0.7f) bits |= (1ULL << jj);
    }
    mask[(size_t)(n * KTOT + i) * MASK_STRIDE + blockIdx.y] = bits;
}

// ---------------- speculative single-wave greedy NMS sweep per image ----------------
// __launch_bounds__(64,1): single wave, up to 512 VGPRs -> the SPEC_D row
// buffers (r0/r1 = 96 VGPRs) stay in registers (round-3 spilled at default
// budget: VGPR_Count=48 -> scratch round-trips serialized the batch loads).
__global__ __launch_bounds__(64, 1) void k_nms(const float* __restrict__ ssc,
                      const float* __restrict__ sbox,
                      const u64* __restrict__ mask, float* __restrict__ out) {
    int n = blockIdx.x, lane = threadIdx.x;
    __shared__ u64 rem[MASK_STRIDE];   // bit set = dead (invalid or suppressed)
    __shared__ int lst[SPEC_D];
    for (int c = 0; c < 79; ++c) {
        int i = c * 64 + lane;
        bool dead = (i >= KTOT) || !(ssc[n * KTOT + i] > -INFINITY);
        u64 db = __ballot(dead);
        if (lane == 0) rem[c] = db;
    }
    if (lane == 0) rem[79] = ~0ULL;
    __syncthreads();

    int picks = 0;
    int cur = 0;   // all words < cur are fully dead (monotone)
    while (picks < 1000 && cur < 79) {
        // ---- scan 64-word window for the SPEC_D lowest alive candidates ----
        int wi = cur + lane;
        u64 alive = (wi < 79) ? ~rem[wi] : 0ULL;
        int pc = __popcll(alive);
        int inc = pc;
        #pragma unroll
        for (int off = 1; off < 64; off <<= 1) {
            int v = __shfl_up(inc, off);
            if (lane >= off) inc += v;
        }
        int tot = __shfl(inc, 63);
        if (tot == 0) { cur += 64; continue; }
        int excl = inc - pc;
        {
            u64 a = alive; int r = excl;
            while (a && r < SPEC_D) {
                int b = __ffsll(a) - 1;
                lst[r] = wi * 64 + b;
                a &= a - 1; r++;
            }
        }
        int batchN = tot < SPEC_D ? tot : SPEC_D;
        __syncthreads();

        // ---- parallel row loads (all independent -> one latency) ----
        u64 r0[SPEC_D], r1[SPEC_D];
        int c0 = lst[0];
        #pragma unroll
        for (int d = 0; d < SPEC_D; ++d) {
            int c = (d < batchN) ? lst[d] : c0;
            const u64* row = &mask[(size_t)(n * KTOT + c) * MASK_STRIDE];
            r0[d] = row[lane];
            r1[d] = (lane < 15) ? row[64 + lane] : 0ULL;
        }
        // box/score prefetch: lane d holds candidate d's output payload
        float bv0 = 0.f, bv1 = 0.f, bv2 = 0.f, bv3 = 0.f, bvs = 0.f;
        if (lane < batchN) {
            int c = lst[lane];
            const float* bp = &sbox[(size_t)(n * KTOT + c) * 4];
            bv0 = bp[0]; bv1 = bp[1]; bv2 = bp[2]; bv3 = bp[3];
            bvs = ssc[n * KTOT + c];
        }

        // ---- sequential commit with in-register batch suppression ----
        u64 supp0 = 0, supp1 = 0;
        u32 cm = 0;
        int base = picks;
        #pragma unroll
        for (int d = 0; d < SPEC_D; ++d) {
            if (d < batchN && picks < 1000) {
                int c = lst[d]; int w = c >> 6, b = c & 63;
                bool deadp = (w < 64) ? ((lane == w) && ((supp0 >> b) & 1))
                                      : ((lane == (w - 64)) && ((supp1 >> b) & 1));
                if (__ballot(deadp) == 0ULL) {
                    supp0 |= r0[d];
                    if (lane < 15) supp1 |= r1[d];
                    cm |= (1u << d);
                    picks++;
                }
            }
        }
        // stores (off the critical chain)
        if (lane < batchN && ((cm >> lane) & 1u)) {
            int pos = base + __popc(cm & ((1u << lane) - 1u));
            float* op = &out[(n * 1000 + pos) * 5];
            op[0] = bv0; op[1] = bv1; op[2] = bv2; op[3] = bv3; op[4] = bvs;
        }
        // ---- apply to dead-map, advance cursor ----
        rem[lane] |= supp0;
        if (lane < 15) rem[64 + lane] |= supp1;
        __syncthreads();
        u64 winAlive = ((cur + lane) < 79) ? ~rem[cur + lane] : 0ULL;
        u64 bal = __ballot(winAlive != 0ULL);
        if (bal == 0ULL) cur += 64;
        else cur += __ffsll(bal) - 1;
        __syncthreads();
    }
    // zero-fill remaining output rows (reference emits zeros for invalid picks)
    int basec = (n * 1000 + picks) * 5, cnt = (1000 - picks) * 5;
    for (int t = lane; t < cnt; t += 64) out[basec + t] = 0.f;
}

// ---------------- workspace layout ----------------
constexpr size_t OFF_MASK   = 0;
constexpr size_t SZ_MASK    = (size_t)NIMG * KTOT * MASK_STRIDE * 8;   // 6,400,000
constexpr size_t OFF_HIST   = OFF_MASK + SZ_MASK;                      // zeroed region start
constexpr size_t OFF_GCNT   = OFF_HIST + 10 * BINS * 4;
constexpr size_t OFF_ECNT   = OFF_GCNT + 64;
constexpr size_t ZERO_WORDS = (10 * BINS * 4 + 128) / 4;               // hist + gcnt + ecnt
constexpr size_t OFF_BINB   = OFF_ECNT + 64;
constexpr size_t OFF_KNEED  = OFF_BINB + 64;
constexpr size_t OFF_G0     = OFF_KNEED + 64;
constexpr size_t OFF_SEL    = OFF_G0 + 64;
constexpr size_t OFF_EQ     = OFF_SEL + 10 * K_PER_LVL * 4;            // 8-aligned
constexpr size_t OFF_KEY64  = OFF_EQ + (size_t)10 * EQ_CAP * 8;
constexpr size_t OFF_CSC    = OFF_KEY64 + (size_t)NIMG * KTOT * 8;
constexpr size_t OFF_CBOX   = OFF_CSC + (size_t)NIMG * KTOT * 4;
constexpr size_t OFF_COBOX  = OFF_CBOX + (size_t)NIMG * KTOT * 16;
constexpr size_t OFF_SSC    = OFF_COBOX + (size_t)NIMG * KTOT * 16;
constexpr size_t OFF_SBOX   = OFF_SSC + (size_t)NIMG * KTOT * 4;
constexpr size_t OFF_SOBOX  = OFF_SBOX + (size_t)NIMG * KTOT * 16;
constexpr size_t WS_NEEDED  = OFF_SOBOX + (size_t)NIMG * KTOT * 16;    // ~7.5 MB

extern "C" void kernel_launch(void* const* d_in, const int* in_sizes, int n_in,
                              void* d_out, int out_size, void* d_ws, size_t ws_size,
                              hipStream_t stream) {
    if (ws_size < WS_NEEDED) return;

    // Detect input ordering from sizes: dict order interleaves (obj0,box0,...)
    bool dictOrder = (in_sizes[1] > in_sizes[0]);
    Ptrs P;
    for (int l = 0; l < 5; ++l) {
        P.o[l] = (const float*)d_in[dictOrder ? (2 * l)     : l];
        P.b[l] = (const float*)d_in[dictOrder ? (2 * l + 1) : (5 + l)];
    }
    char* ws = (char*)d_ws;
    u64*   mask   = (u64*)(ws + OFF_MASK);
    u32*   hist   = (u32*)(ws + OFF_HIST);
    u32*   gcnt   = (u32*)(ws + OFF_GCNT);
    u32*   ecnt   = (u32*)(ws + OFF_ECNT);
    int*   binB   = (int*)(ws + OFF_BINB);
    int*   kneed  = (int*)(ws + OFF_KNEED);
    int*   g0     = (int*)(ws + OFF_G0);
    int*   sel    = (int*)(ws + OFF_SEL);
    u64*   eq     = (u64*)(ws + OFF_EQ);
    u64*   key64  = (u64*)(ws + OFF_KEY64);
    float* csc    = (float*)(ws + OFF_CSC);
    float* cbox   = (float*)(ws + OFF_CBOX);
    float* cobox  = (float*)(ws + OFF_COBOX);
    float* ssc    = (float*)(ws + OFF_SSC);
    float* sbox   = (float*)(ws + OFF_SBOX);
    float* sobox  = (float*)(ws + OFF_SOBOX);
    float* out    = (float*)d_out;

    k_zero<<<dim3(21), 256, 0, stream>>>(hist, (int)ZERO_WORDS);       // hist + gcnt + ecnt
    k_hist<<<dim3(32, 10), 256, 0, stream>>>(P, hist);
    k_resolve<<<10, 256, 0, stream>>>(hist, binB, kneed, g0);
    k_compact<<<dim3(64, 10), 256, 0, stream>>>(P, binB, gcnt, ecnt, sel, eq);
    k_eqsel<<<10, 256, 0, stream>>>(ecnt, kneed, g0, eq, sel);
    k_feat<<<dim3((NIMG * KTOT + 255) / 256), 256, 0, stream>>>(P, sel, key64, csc, cbox, cobox);
    k_rank<<<dim3((KTOT + 255) / 256, NIMG), 256, 0, stream>>>(key64, csc, cbox, cobox, ssc, sbox, sobox);
    k_mask<<<dim3(79, 79, NIMG), 64, 0, stream>>>(sobox, mask);
    k_nms<<<NIMG, 64, 0, stream>>>(ssc, sbox, mask, out);
}

// Round 6
// 612.553 us; speedup vs baseline: 1.5968x; 1.0684x over previous
//
#include <hip/hip_runtime.h>
#include <cmath>

#pragma clang fp contract(off)

typedef unsigned int u32;
typedef unsigned long long u64;

#define K_PER_LVL 1000
#define KTOT 5000            // 5 levels * 1000
#define NIMG 2
#define MASK_STRIDE 80       // u64 words per mask row (79 used, 1 pad)
#define BINS 2048            // histogram bins = top 11 bits of fkey
#define BIN_SHIFT 21
#define EQ_CAP 2048
#define BATCH 48             // NMS batch size (rows DMA'd to LDS per iteration)
#define ROWW 128             // u64 words per LDS row slot (1024 B; DMA writes lane*16)

__constant__ int c_LG[5] = {512, 256, 128, 64, 32};      // grid dim (square)
__constant__ int c_LS[5] = {4, 8, 16, 32, 64};           // stride
__constant__ int c_LZ[5] = {32, 64, 128, 256, 512};      // anchor size
__constant__ int c_LM[5] = {786432, 196608, 49152, 12288, 3072}; // 3*G*G

struct Ptrs { const float* o[5]; const float* b[5]; };

// monotone float -> uint key (larger float => larger key)
__device__ inline u32 fkey(float f) {
    u32 u = __float_as_uint(f);
    return (u & 0x80000000u) ? ~u : (u | 0x80000000u);
}

// ---------------- zero hist + counters ----------------
__global__ __launch_bounds__(256) void k_zero(u32* __restrict__ z, int nwords) {
    int i = blockIdx.x * 256 + threadIdx.x;
    int stride = gridDim.x * 256;
    for (; i < nwords; i += stride) z[i] = 0;
}

// ---------------- one-pass 2048-bin histogram (float4 loads, LDS pre-agg) ----------------
__global__ __launch_bounds__(256) void k_hist(Ptrs P, u32* __restrict__ hist) {
    int p = blockIdx.y; int l = p % 5; int n = p / 5;
    int M4 = c_LM[l] >> 2;
    const float4* base = (const float4*)(P.o[l] + (size_t)n * c_LM[l]);
    __shared__ u32 lh[BINS];
    for (int i = threadIdx.x; i < BINS; i += 256) lh[i] = 0;
    __syncthreads();
    int stride = gridDim.x * 256;
    for (int i = blockIdx.x * 256 + threadIdx.x; i < M4; i += stride) {
        float4 v = base[i];
        atomicAdd(&lh[fkey(v.x) >> BIN_SHIFT], 1u);
        atomicAdd(&lh[fkey(v.y) >> BIN_SHIFT], 1u);
        atomicAdd(&lh[fkey(v.z) >> BIN_SHIFT], 1u);
        atomicAdd(&lh[fkey(v.w) >> BIN_SHIFT], 1u);
    }
    __syncthreads();
    for (int i = threadIdx.x; i < BINS; i += 256) {
        u32 c = lh[i];
        if (c) atomicAdd(&hist[p * BINS + i], c);
    }
}

// ---------------- resolve: threshold bin B, G = #(keys above B), KF = 1000 - G ----------------
__global__ __launch_bounds__(256) void k_resolve(const u32* __restrict__ hist,
                                                 int* __restrict__ binB, int* __restrict__ kneed,
                                                 int* __restrict__ g0) {
    int p = blockIdx.x, t = threadIdx.x;
    __shared__ u32 lh[BINS];
    __shared__ u32 seg[256];
    for (int i = t; i < BINS; i += 256) lh[i] = hist[p * BINS + i];
    __syncthreads();
    u32 s = 0;
    for (int q = 0; q < 8; ++q) s += lh[t * 8 + q];
    seg[t] = s;
    __syncthreads();
    if (t == 0) {
        u32 G = 0; int B = 0;
        for (int sg = 255; sg >= 0; --sg) {
            if (G + seg[sg] >= (u32)K_PER_LVL) {
                for (int b = sg * 8 + 7; b >= sg * 8; --b) {
                    u32 c = lh[b];
                    if (G + c >= (u32)K_PER_LVL) { B = b; break; }
                    G += c;
                }
                break;
            }
            G += seg[sg];
        }
        binB[p] = B;
        kneed[p] = K_PER_LVL - (int)G;   // KF taken from boundary bin
        g0[p] = (int)G;                  // count strictly above bin B
    }
}

// ---------------- compact: bin>B -> sel front; bin==B -> eq (packed key|~m) ----------------
__global__ __launch_bounds__(256) void k_compact(Ptrs P, const int* __restrict__ binB,
                                                 u32* gcnt, u32* ecnt,
                                                 int* __restrict__ sel, u64* __restrict__ eq) {
    int p = blockIdx.y; int l = p % 5; int n = p / 5;
    int M4 = c_LM[l] >> 2; int gg = c_LM[l] / 3;
    const float4* base = (const float4*)(P.o[l] + (size_t)n * c_LM[l]);
    int B = binB[p];
    int stride = gridDim.x * 256;
    for (int i4 = blockIdx.x * 256 + threadIdx.x; i4 < M4; i4 += stride) {
        float4 v = base[i4];
        float vv[4] = {v.x, v.y, v.z, v.w};
        #pragma unroll
        for (int q = 0; q < 4; ++q) {
            u32 k = fkey(vv[q]);
            int bin = (int)(k >> BIN_SHIFT);
            if (bin < B) continue;
            int i = i4 * 4 + q;
            // input linear i = a*gg + pix ; flattened m = pix*3 + a  (h,w,a order)
            int a = i / gg; int pix = i - a * gg; int m = pix * 3 + a;
            if (bin > B) {
                u32 pos = atomicAdd(&gcnt[p], 1u);
                sel[p * K_PER_LVL + pos] = m;
            } else {
                u32 e = atomicAdd(&ecnt[p], 1u);
                if (e < EQ_CAP) eq[(size_t)p * EQ_CAP + e] = ((u64)k << 20) | (u64)(0xFFFFFu ^ (u32)m);
            }
        }
    }
}

// ---------------- boundary bin: exact order (key desc, m asc) via LDS bitonic, take KF ----------------
__global__ __launch_bounds__(256) void k_eqsel(const u32* __restrict__ ecnt, const int* __restrict__ kneed,
                                               const int* __restrict__ g0,
                                               const u64* __restrict__ eq, int* __restrict__ sel) {
    int p = blockIdx.x, t = threadIdx.x;
    int E = (int)ecnt[p]; if (E > EQ_CAP) E = EQ_CAP;
    int KF = kneed[p]; int G0 = g0[p];
    __shared__ u64 a[EQ_CAP];
    for (int i = t; i < EQ_CAP; i += 256) a[i] = (i < E) ? eq[(size_t)p * EQ_CAP + i] : 0ULL;
    __syncthreads();
    for (int k = 2; k <= EQ_CAP; k <<= 1) {
        for (int j = k >> 1; j > 0; j >>= 1) {
            for (int i = t; i < EQ_CAP; i += 256) {
                int x = i ^ j;
                if (x > i) {
                    u64 va = a[i], vb = a[x];
                    bool up = (i & k) == 0;                 // descending sort
                    bool sw = up ? (va < vb) : (va > vb);
                    if (sw) { a[i] = vb; a[x] = va; }
                }
            }
            __syncthreads();
        }
    }
    for (int r = t; r < KF; r += 256) {
        int m = (int)(0xFFFFFu ^ (u32)(a[r] & 0xFFFFFu));
        sel[p * K_PER_LVL + G0 + r] = m;
    }
}

// ---------------- featurize: anchors + decode + clip + score + 64b order key ----------------
__global__ void k_feat(Ptrs P, const int* __restrict__ sel, u64* __restrict__ key64,
                       float* __restrict__ csc, float* __restrict__ cbox, float* __restrict__ cobox) {
    int tid = blockIdx.x * 256 + threadIdx.x;
    if (tid >= NIMG * KTOT) return;
    int p = tid / K_PER_LVL, s = tid - p * K_PER_LVL;
    int n = p / 5, l = p % 5;
    int G = c_LG[l], S = c_LS[l], Z = c_LZ[l];
    int gg = G * G;
    int m = sel[p * K_PER_LVL + s];
    int a = m % 3; int pix = m / 3; int h = pix / G; int w = pix - h * G;

    // anchor base: hr=sqrt(ar), wr=1/hr, round-half-even (matches jnp f32)
    const float ars[3] = {0.5f, 1.0f, 2.0f};
    float ar = ars[a];
    float hr = sqrtf(ar), wr = 1.0f / hr;
    float wsz = wr * (float)Z, hsz = hr * (float)Z;
    float bx1 = rintf(-0.5f * wsz), by1 = rintf(-0.5f * hsz);
    float bx2 = rintf(0.5f * wsz),  by2 = rintf(0.5f * hsz);
    float sx = (float)(w * S), sy = (float)(h * S);
    float ax1 = sx + bx1, ay1 = sy + by1, ax2 = sx + bx2, ay2 = sy + by2;
    float wa = ax2 - ax1, ha = ay2 - ay1;
    float cxa = ax1 + 0.5f * wa, cya = ay1 + 0.5f * ha;

    const float* bb = P.b[l] + (size_t)n * 12 * gg;
    float dx = bb[(a * 4 + 0) * gg + pix];
    float dy = bb[(a * 4 + 1) * gg + pix];
    const float CLIPV = 4.135166556742356f;  // log(1000/16)
    float dw = fminf(bb[(a * 4 + 2) * gg + pix], CLIPV);
    float dh = fminf(bb[(a * 4 + 3) * gg + pix], CLIPV);
    float cx = dx * wa + cxa, cy = dy * ha + cya;
    float ww = expf(dw) * wa, hh = expf(dh) * ha;
    float x1 = cx - 0.5f * ww, y1 = cy - 0.5f * hh;
    float x2 = cx + 0.5f * ww, y2 = cy + 0.5f * hh;
    x1 = fminf(fmaxf(x1, 0.f), 2048.f);
    y1 = fminf(fmaxf(y1, 0.f), 2048.f);
    x2 = fminf(fmaxf(x2, 0.f), 2048.f);
    y2 = fminf(fmaxf(y2, 0.f), 2048.f);

    float raw = P.o[l][(size_t)n * 3 * gg + a * gg + pix];
    float sc = 1.0f / (1.0f + expf(-raw));
    bool keep = (x2 - x1 >= 1e-3f) && (y2 - y1 >= 1e-3f) && (sc > 0.0f);

    int slot = n * KTOT + l * K_PER_LVL + s;
    // total order key: raw desc, then (level asc, m asc) == reference concat-position order
    u32 tb = ((u32)l << 20) | (u32)m;          // m < 2^20, l < 8  -> 23 bits, unique
    u32 kk = keep ? fkey(raw) : 0u;            // invalid sinks below every valid (finite raw)
    key64[slot] = ((u64)kk << 23) | (u64)(tb ^ 0x7FFFFFu);

    csc[slot] = keep ? sc : -INFINITY;
    cbox[slot * 4 + 0] = x1; cbox[slot * 4 + 1] = y1;
    cbox[slot * 4 + 2] = x2; cbox[slot * 4 + 3] = y2;
    float off = 4097.0f * (float)l;            // lvl * (W+H+1), batched_nms offset
    cobox[slot * 4 + 0] = x1 + off; cobox[slot * 4 + 1] = y1 + off;
    cobox[slot * 4 + 2] = x2 + off; cobox[slot * 4 + 3] = y2 + off;
}

// ---------------- exact rank by counting (LDS-staged keys), scatter ----------------
__global__ __launch_bounds__(256) void k_rank(const u64* __restrict__ key64, const float* __restrict__ csc,
                       const float* __restrict__ cbox, const float* __restrict__ cobox,
                       float* __restrict__ ssc, float* __restrict__ sbox, float* __restrict__ sobox) {
    int n = blockIdx.y;
    __shared__ u64 kk[KTOT];                     // 40 KB
    for (int t = threadIdx.x; t < KTOT; t += 256) kk[t] = key64[(size_t)n * KTOT + t];
    __syncthreads();
    int i = blockIdx.x * 256 + threadIdx.x;
    if (i >= KTOT) return;
    u64 ki = kk[i];
    int rank = 0;
    for (int j = 0; j < KTOT; ++j) rank += (kk[j] > ki) ? 1 : 0;   // lockstep j -> LDS broadcast
    int src = n * KTOT + i, dst = n * KTOT + rank;
    ssc[dst] = csc[src];
    sbox[dst * 4 + 0] = cbox[src * 4 + 0]; sbox[dst * 4 + 1] = cbox[src * 4 + 1];
    sbox[dst * 4 + 2] = cbox[src * 4 + 2]; sbox[dst * 4 + 3] = cbox[src * 4 + 3];
    sobox[dst * 4 + 0] = cobox[src * 4 + 0]; sobox[dst * 4 + 1] = cobox[src * 4 + 1];
    sobox[dst * 4 + 2] = cobox[src * 4 + 2]; sobox[dst * 4 + 3] = cobox[src * 4 + 3];
}

// ---------------- IoU suppression bitmask matrix ----------------
__global__ void k_mask(const float* __restrict__ sobox, u64* __restrict__ mask) {
    int n = blockIdx.z;
    int i = blockIdx.x * 64 + threadIdx.x;
    int j0 = blockIdx.y * 64;
    __shared__ float cb[64][4];
    int jl = j0 + threadIdx.x;
    if (jl < KTOT) {
        cb[threadIdx.x][0] = sobox[(size_t)(n * KTOT + jl) * 4 + 0];
        cb[threadIdx.x][1] = sobox[(size_t)(n * KTOT + jl) * 4 + 1];
        cb[threadIdx.x][2] = sobox[(size_t)(n * KTOT + jl) * 4 + 2];
        cb[threadIdx.x][3] = sobox[(size_t)(n * KTOT + jl) * 4 + 3];
    } else {
        cb[threadIdx.x][0] = 0.f; cb[threadIdx.x][1] = 0.f;
        cb[threadIdx.x][2] = 0.f; cb[threadIdx.x][3] = 0.f;
    }
    __syncthreads();
    if (i >= KTOT) return;
    float x1 = sobox[(size_t)(n * KTOT + i) * 4 + 0];
    float y1 = sobox[(size_t)(n * KTOT + i) * 4 + 1];
    float x2 = sobox[(size_t)(n * KTOT + i) * 4 + 2];
    float y2 = sobox[(size_t)(n * KTOT + i) * 4 + 3];
    float areai = fmaxf(x2 - x1, 0.f) * fmaxf(y2 - y1, 0.f);
    u64 bits = 0;
    int lim = KTOT - j0; if (lim > 64) lim = 64;
    for (int jj = 0; jj < lim; ++jj) {
        float bx1 = cb[jj][0], by1 = cb[jj][1], bx2 = cb[jj][2], by2 = cb[jj][3];
        float areaj = fmaxf(bx2 - bx1, 0.f) * fmaxf(by2 - by1, 0.f);
        float ltx = fmaxf(x1, bx1), lty = fmaxf(y1, by1);
        float rbx = fminf(x2, bx2), rby = fminf(y2, by2);
        float iw = fmaxf(rbx - ltx, 0.f), ih = fmaxf(rby - lty, 0.f);
        float inter = iw * ih;
        float iou = inter / (areai + areaj - inter + 1e-9f);
        if (iou > 0.7f) bits |= (1ULL << jj);
    }
    mask[(size_t)(n * KTOT + i) * MASK_STRIDE + blockIdx.y] = bits;
}

// ---------------- batched greedy NMS: LDS row staging via global_load_lds DMA ----------------
// Exact greedy: per batch take next BATCH alive candidates (rank order), DMA all
// their mask rows global->LDS (one size=16 instr per row, zero VGPR payload, one
// latency), build 48x48 suppression columns (one u64/lane, no private arrays ->
// no scratch spill), serial-commit closure in registers, union to dead map.
__global__ __launch_bounds__(64, 1) void k_nms(const float* __restrict__ ssc,
                      const float* __restrict__ sbox,
                      const u64* __restrict__ mask, float* __restrict__ out) {
    int n = blockIdx.x, lane = threadIdx.x;
    __shared__ u64 rows[BATCH * ROWW];           // 48 KB row staging
    __shared__ u64 rem[MASK_STRIDE];             // bit set = dead
    __shared__ int lst[BATCH];
    for (int c = 0; c < 79; ++c) {
        int i = c * 64 + lane;
        bool dead = (i >= KTOT) || !(ssc[n * KTOT + i] > -INFINITY);
        u64 db = __ballot(dead);
        if (lane == 0) rem[c] = db;
    }
    if (lane == 0) rem[79] = ~0ULL;
    __syncthreads();

    int picks = 0, cur = 0;
    while (picks < 1000 && cur < 79) {
        // ---- gather next BATCH alive candidates (ascending rank) ----
        int have = 0, scanw = cur;
        while (have < BATCH && scanw < 79) {
            int wi = scanw + lane;
            u64 alive = (wi < 79) ? ~rem[wi] : 0ULL;
            int pc = __popcll(alive);
            int inc = pc;
            #pragma unroll
            for (int off = 1; off < 64; off <<= 1) {
                int v = __shfl_up(inc, off);
                if (lane >= off) inc += v;
            }
            int excl = have + inc - pc;
            u64 a = alive; int t = 0;
            while (a && (excl + t) < BATCH) {
                int b = __ffsll(a) - 1;
                lst[excl + t] = wi * 64 + b;
                a &= a - 1; ++t;
            }
            int tot = __shfl(inc, 63);
            have += tot; if (have > BATCH) have = BATCH;
            scanw += 64;
        }
        __syncthreads();
        if (have == 0) break;
        int batchN = have;

        // ---- async DMA: row d -> rows[d*ROWW], lane writes bytes lane*16.. ----
        for (int d = 0; d < batchN; ++d) {
            int c = lst[d];
            const u32* g = (const u32*)(mask + (size_t)(n * KTOT + c) * MASK_STRIDE) + lane * 4;
            __builtin_amdgcn_global_load_lds(
                (const __attribute__((address_space(1))) u32*)g,
                (__attribute__((address_space(3))) u32*)(rows + (size_t)d * ROWW),
                16, 0, 0);
        }
        asm volatile("s_waitcnt vmcnt(0)" ::: "memory");
        __syncthreads();

        // ---- suppression columns: col bit e = (row_e suppresses candidate lane) ----
        u64 col = 0;
        if (lane < batchN) {
            int cd = lst[lane], wd = cd >> 6, bd = cd & 63;
            #pragma unroll 8
            for (int e = 0; e < batchN; ++e)
                col |= ((rows[(size_t)e * ROWW + wd] >> bd) & 1ULL) << e;
        }
        // ---- serial greedy closure (all lanes redundantly, registers only) ----
        u64 cm = 0;
        for (int e = 0; e < batchN; ++e) {
            u64 ce = __shfl(col, e);
            if ((cm & ce) == 0ULL) cm |= (1ULL << e);
        }
        int allowed = 1000 - picks;
        int ncom = __popcll(cm);
        while (ncom > allowed) { cm &= ~(1ULL << (63 - __clzll(cm))); --ncom; }

        // ---- outputs: lane d writes its committed candidate ----
        if (lane < batchN && ((cm >> lane) & 1ULL)) {
            int c = lst[lane];
            int pos = picks + (int)__popcll(cm & ((1ULL << lane) - 1ULL));
            const float* bp = &sbox[(size_t)(n * KTOT + c) * 4];
            float* op = &out[(n * 1000 + pos) * 5];
            op[0] = bp[0]; op[1] = bp[1]; op[2] = bp[2]; op[3] = bp[3];
            op[4] = ssc[n * KTOT + c];
        }
        picks += ncom;

        // ---- union committed rows -> dead map (kills suppressed + committed) ----
        u64 supp0 = 0, supp1 = 0;
        for (int e = 0; e < batchN; ++e) if ((cm >> e) & 1ULL) {
            supp0 |= rows[(size_t)e * ROWW + lane];
            if (lane < 16) supp1 |= rows[(size_t)e * ROWW + 64 + lane];
        }
        rem[lane] |= supp0;
        if (lane < 16) rem[64 + lane] |= supp1;
        __syncthreads();
        u64 winAlive = ((cur + lane) < 79) ? ~rem[cur + lane] : 0ULL;
        u64 bal = __ballot(winAlive != 0ULL);
        if (bal == 0ULL) cur += 64;
        else cur += __ffsll(bal) - 1;
        __syncthreads();
    }
    // zero-fill remaining output rows (reference emits zeros for invalid picks)
    int basec = (n * 1000 + picks) * 5, cnt = (1000 - picks) * 5;
    for (int t = lane; t < cnt; t += 64) out[basec + t] = 0.f;
}

// ---------------- workspace layout ----------------
constexpr size_t OFF_MASK   = 0;
constexpr size_t SZ_MASK    = (size_t)NIMG * KTOT * MASK_STRIDE * 8;   // 6,400,000
constexpr size_t OFF_HIST   = OFF_MASK + SZ_MASK;                      // zeroed region start
constexpr size_t OFF_GCNT   = OFF_HIST + 10 * BINS * 4;
constexpr size_t OFF_ECNT   = OFF_GCNT + 64;
constexpr size_t ZERO_WORDS = (10 * BINS * 4 + 128) / 4;               // hist + gcnt + ecnt
constexpr size_t OFF_BINB   = OFF_ECNT + 64;
constexpr size_t OFF_KNEED  = OFF_BINB + 64;
constexpr size_t OFF_G0     = OFF_KNEED + 64;
constexpr size_t OFF_SEL    = OFF_G0 + 64;
constexpr size_t OFF_EQ     = OFF_SEL + 10 * K_PER_LVL * 4;            // 8-aligned
constexpr size_t OFF_KEY64  = OFF_EQ + (size_t)10 * EQ_CAP * 8;
constexpr size_t OFF_CSC    = OFF_KEY64 + (size_t)NIMG * KTOT * 8;
constexpr size_t OFF_CBOX   = OFF_CSC + (size_t)NIMG * KTOT * 4;
constexpr size_t OFF_COBOX  = OFF_CBOX + (size_t)NIMG * KTOT * 16;
constexpr size_t OFF_SSC    = OFF_COBOX + (size_t)NIMG * KTOT * 16;
constexpr size_t OFF_SBOX   = OFF_SSC + (size_t)NIMG * KTOT * 4;
constexpr size_t OFF_SOBOX  = OFF_SBOX + (size_t)NIMG * KTOT * 16;
constexpr size_t WS_NEEDED  = OFF_SOBOX + (size_t)NIMG * KTOT * 16;    // ~7.5 MB

extern "C" void kernel_launch(void* const* d_in, const int* in_sizes, int n_in,
                              void* d_out, int out_size, void* d_ws, size_t ws_size,
                              hipStream_t stream) {
    if (ws_size < WS_NEEDED) return;

    // Detect input ordering from sizes: dict order interleaves (obj0,box0,...)
    bool dictOrder = (in_sizes[1] > in_sizes[0]);
    Ptrs P;
    for (int l = 0; l < 5; ++l) {
        P.o[l] = (const float*)d_in[dictOrder ? (2 * l)     : l];
        P.b[l] = (const float*)d_in[dictOrder ? (2 * l + 1) : (5 + l)];
    }
    char* ws = (char*)d_ws;
    u64*   mask   = (u64*)(ws + OFF_MASK);
    u32*   hist   = (u32*)(ws + OFF_HIST);
    u32*   gcnt   = (u32*)(ws + OFF_GCNT);
    u32*   ecnt   = (u32*)(ws + OFF_ECNT);
    int*   binB   = (int*)(ws + OFF_BINB);
    int*   kneed  = (int*)(ws + OFF_KNEED);
    int*   g0     = (int*)(ws + OFF_G0);
    int*   sel    = (int*)(ws + OFF_SEL);
    u64*   eq     = (u64*)(ws + OFF_EQ);
    u64*   key64  = (u64*)(ws + OFF_KEY64);
    float* csc    = (float*)(ws + OFF_CSC);
    float* cbox   = (float*)(ws + OFF_CBOX);
    float* cobox  = (float*)(ws + OFF_COBOX);
    float* ssc    = (float*)(ws + OFF_SSC);
    float* sbox   = (float*)(ws + OFF_SBOX);
    float* sobox  = (float*)(ws + OFF_SOBOX);
    float* out    = (float*)d_out;

    k_zero<<<dim3(21), 256, 0, stream>>>(hist, (int)ZERO_WORDS);       // hist + gcnt + ecnt
    k_hist<<<dim3(32, 10), 256, 0, stream>>>(P, hist);
    k_resolve<<<10, 256, 0, stream>>>(hist, binB, kneed, g0);
    k_compact<<<dim3(64, 10), 256, 0, stream>>>(P, binB, gcnt, ecnt, sel, eq);
    k_eqsel<<<10, 256, 0, stream>>>(ecnt, kneed, g0, eq, sel);
    k_feat<<<dim3((NIMG * KTOT + 255) / 256), 256, 0, stream>>>(P, sel, key64, csc, cbox, cobox);
    k_rank<<<dim3((KTOT + 255) / 256, NIMG), 256, 0, stream>>>(key64, csc, cbox, cobox, ssc, sbox, sobox);
    k_mask<<<dim3(79, 79, NIMG), 64, 0, stream>>>(sobox, mask);
    k_nms<<<NIMG, 64, 0, stream>>>(ssc, sbox, mask, out);
}

// Round 7
// 593.497 us; speedup vs baseline: 1.6480x; 1.0321x over previous
//
#include <hip/hip_runtime.h>
#include <cmath>

#pragma clang fp contract(off)

typedef unsigned int u32;
typedef unsigned long long u64;

#define K_PER_LVL 1000
#define KTOT 5000            // 5 levels * 1000
#define NIMG 2
#define MASK_STRIDE 80       // u64 words per mask row (79 used, 1 pad)
#define BINS 2048            // histogram bins = top 11 bits of fkey
#define BIN_SHIFT 21
#define EQ_CAP 2048
#define BATCH 64             // NMS batch size (rows staged to LDS per iteration)

__constant__ int c_LG[5] = {512, 256, 128, 64, 32};      // grid dim (square)
__constant__ int c_LS[5] = {4, 8, 16, 32, 64};           // stride
__constant__ int c_LZ[5] = {32, 64, 128, 256, 512};      // anchor size
__constant__ int c_LM[5] = {786432, 196608, 49152, 12288, 3072}; // 3*G*G

struct Ptrs { const float* o[5]; const float* b[5]; };

// monotone float -> uint key (larger float => larger key)
__device__ inline u32 fkey(float f) {
    u32 u = __float_as_uint(f);
    return (u & 0x80000000u) ? ~u : (u | 0x80000000u);
}

// ---------------- zero hist + counters ----------------
__global__ __launch_bounds__(256) void k_zero(u32* __restrict__ z, int nwords) {
    int i = blockIdx.x * 256 + threadIdx.x;
    int stride = gridDim.x * 256;
    for (; i < nwords; i += stride) z[i] = 0;
}

// ---------------- one-pass 2048-bin histogram (float4 loads, LDS pre-agg) ----------------
__global__ __launch_bounds__(256) void k_hist(Ptrs P, u32* __restrict__ hist) {
    int p = blockIdx.y; int l = p % 5; int n = p / 5;
    int M4 = c_LM[l] >> 2;
    const float4* base = (const float4*)(P.o[l] + (size_t)n * c_LM[l]);
    __shared__ u32 lh[BINS];
    for (int i = threadIdx.x; i < BINS; i += 256) lh[i] = 0;
    __syncthreads();
    int stride = gridDim.x * 256;
    for (int i = blockIdx.x * 256 + threadIdx.x; i < M4; i += stride) {
        float4 v = base[i];
        atomicAdd(&lh[fkey(v.x) >> BIN_SHIFT], 1u);
        atomicAdd(&lh[fkey(v.y) >> BIN_SHIFT], 1u);
        atomicAdd(&lh[fkey(v.z) >> BIN_SHIFT], 1u);
        atomicAdd(&lh[fkey(v.w) >> BIN_SHIFT], 1u);
    }
    __syncthreads();
    for (int i = threadIdx.x; i < BINS; i += 256) {
        u32 c = lh[i];
        if (c) atomicAdd(&hist[p * BINS + i], c);
    }
}

// ---------------- resolve: threshold bin B, G = #(keys above B), KF = 1000 - G ----------------
__global__ __launch_bounds__(256) void k_resolve(const u32* __restrict__ hist,
                                                 int* __restrict__ binB, int* __restrict__ kneed,
                                                 int* __restrict__ g0) {
    int p = blockIdx.x, t = threadIdx.x;
    __shared__ u32 lh[BINS];
    __shared__ u32 seg[256];
    for (int i = t; i < BINS; i += 256) lh[i] = hist[p * BINS + i];
    __syncthreads();
    u32 s = 0;
    for (int q = 0; q < 8; ++q) s += lh[t * 8 + q];
    seg[t] = s;
    __syncthreads();
    if (t == 0) {
        u32 G = 0; int B = 0;
        for (int sg = 255; sg >= 0; --sg) {
            if (G + seg[sg] >= (u32)K_PER_LVL) {
                for (int b = sg * 8 + 7; b >= sg * 8; --b) {
                    u32 c = lh[b];
                    if (G + c >= (u32)K_PER_LVL) { B = b; break; }
                    G += c;
                }
                break;
            }
            G += seg[sg];
        }
        binB[p] = B;
        kneed[p] = K_PER_LVL - (int)G;   // KF taken from boundary bin
        g0[p] = (int)G;                  // count strictly above bin B
    }
}

// ---------------- compact: bin>B -> sel front; bin==B -> eq (packed key|~m) ----------------
__global__ __launch_bounds__(256) void k_compact(Ptrs P, const int* __restrict__ binB,
                                                 u32* gcnt, u32* ecnt,
                                                 int* __restrict__ sel, u64* __restrict__ eq) {
    int p = blockIdx.y; int l = p % 5; int n = p / 5;
    int M4 = c_LM[l] >> 2; int gg = c_LM[l] / 3;
    const float4* base = (const float4*)(P.o[l] + (size_t)n * c_LM[l]);
    int B = binB[p];
    int stride = gridDim.x * 256;
    for (int i4 = blockIdx.x * 256 + threadIdx.x; i4 < M4; i4 += stride) {
        float4 v = base[i4];
        float vv[4] = {v.x, v.y, v.z, v.w};
        #pragma unroll
        for (int q = 0; q < 4; ++q) {
            u32 k = fkey(vv[q]);
            int bin = (int)(k >> BIN_SHIFT);
            if (bin < B) continue;
            int i = i4 * 4 + q;
            // input linear i = a*gg + pix ; flattened m = pix*3 + a  (h,w,a order)
            int a = i / gg; int pix = i - a * gg; int m = pix * 3 + a;
            if (bin > B) {
                u32 pos = atomicAdd(&gcnt[p], 1u);
                sel[p * K_PER_LVL + pos] = m;
            } else {
                u32 e = atomicAdd(&ecnt[p], 1u);
                if (e < EQ_CAP) eq[(size_t)p * EQ_CAP + e] = ((u64)k << 20) | (u64)(0xFFFFFu ^ (u32)m);
            }
        }
    }
}

// ---------------- boundary bin: exact order (key desc, m asc) via LDS bitonic, take KF ----------------
__global__ __launch_bounds__(256) void k_eqsel(const u32* __restrict__ ecnt, const int* __restrict__ kneed,
                                               const int* __restrict__ g0,
                                               const u64* __restrict__ eq, int* __restrict__ sel) {
    int p = blockIdx.x, t = threadIdx.x;
    int E = (int)ecnt[p]; if (E > EQ_CAP) E = EQ_CAP;
    int KF = kneed[p]; int G0 = g0[p];
    __shared__ u64 a[EQ_CAP];
    for (int i = t; i < EQ_CAP; i += 256) a[i] = (i < E) ? eq[(size_t)p * EQ_CAP + i] : 0ULL;
    __syncthreads();
    for (int k = 2; k <= EQ_CAP; k <<= 1) {
        for (int j = k >> 1; j > 0; j >>= 1) {
            for (int i = t; i < EQ_CAP; i += 256) {
                int x = i ^ j;
                if (x > i) {
                    u64 va = a[i], vb = a[x];
                    bool up = (i & k) == 0;                 // descending sort
                    bool sw = up ? (va < vb) : (va > vb);
                    if (sw) { a[i] = vb; a[x] = va; }
                }
            }
            __syncthreads();
        }
    }
    for (int r = t; r < KF; r += 256) {
        int m = (int)(0xFFFFFu ^ (u32)(a[r] & 0xFFFFFu));
        sel[p * K_PER_LVL + G0 + r] = m;
    }
}

// ---------------- featurize: anchors + decode + clip + score + 64b order key ----------------
__global__ void k_feat(Ptrs P, const int* __restrict__ sel, u64* __restrict__ key64,
                       float* __restrict__ csc, float* __restrict__ cbox, float* __restrict__ cobox) {
    int tid = blockIdx.x * 256 + threadIdx.x;
    if (tid >= NIMG * KTOT) return;
    int p = tid / K_PER_LVL, s = tid - p * K_PER_LVL;
    int n = p / 5, l = p % 5;
    int G = c_LG[l], S = c_LS[l], Z = c_LZ[l];
    int gg = G * G;
    int m = sel[p * K_PER_LVL + s];
    int a = m % 3; int pix = m / 3; int h = pix / G; int w = pix - h * G;

    // anchor base: hr=sqrt(ar), wr=1/hr, round-half-even (matches jnp f32)
    const float ars[3] = {0.5f, 1.0f, 2.0f};
    float ar = ars[a];
    float hr = sqrtf(ar), wr = 1.0f / hr;
    float wsz = wr * (float)Z, hsz = hr * (float)Z;
    float bx1 = rintf(-0.5f * wsz), by1 = rintf(-0.5f * hsz);
    float bx2 = rintf(0.5f * wsz),  by2 = rintf(0.5f * hsz);
    float sx = (float)(w * S), sy = (float)(h * S);
    float ax1 = sx + bx1, ay1 = sy + by1, ax2 = sx + bx2, ay2 = sy + by2;
    float wa = ax2 - ax1, ha = ay2 - ay1;
    float cxa = ax1 + 0.5f * wa, cya = ay1 + 0.5f * ha;

    const float* bb = P.b[l] + (size_t)n * 12 * gg;
    float dx = bb[(a * 4 + 0) * gg + pix];
    float dy = bb[(a * 4 + 1) * gg + pix];
    const float CLIPV = 4.135166556742356f;  // log(1000/16)
    float dw = fminf(bb[(a * 4 + 2) * gg + pix], CLIPV);
    float dh = fminf(bb[(a * 4 + 3) * gg + pix], CLIPV);
    float cx = dx * wa + cxa, cy = dy * ha + cya;
    float ww = expf(dw) * wa, hh = expf(dh) * ha;
    float x1 = cx - 0.5f * ww, y1 = cy - 0.5f * hh;
    float x2 = cx + 0.5f * ww, y2 = cy + 0.5f * hh;
    x1 = fminf(fmaxf(x1, 0.f), 2048.f);
    y1 = fminf(fmaxf(y1, 0.f), 2048.f);
    x2 = fminf(fmaxf(x2, 0.f), 2048.f);
    y2 = fminf(fmaxf(y2, 0.f), 2048.f);

    float raw = P.o[l][(size_t)n * 3 * gg + a * gg + pix];
    float sc = 1.0f / (1.0f + expf(-raw));
    bool keep = (x2 - x1 >= 1e-3f) && (y2 - y1 >= 1e-3f) && (sc > 0.0f);

    int slot = n * KTOT + l * K_PER_LVL + s;
    // total order key: raw desc, then (level asc, m asc) == reference concat-position order
    u32 tb = ((u32)l << 20) | (u32)m;          // m < 2^20, l < 8  -> 23 bits, unique
    u32 kk = keep ? fkey(raw) : 0u;            // invalid sinks below every valid (finite raw)
    key64[slot] = ((u64)kk << 23) | (u64)(tb ^ 0x7FFFFFu);

    csc[slot] = keep ? sc : -INFINITY;
    cbox[slot * 4 + 0] = x1; cbox[slot * 4 + 1] = y1;
    cbox[slot * 4 + 2] = x2; cbox[slot * 4 + 3] = y2;
    float off = 4097.0f * (float)l;            // lvl * (W+H+1), batched_nms offset
    cobox[slot * 4 + 0] = x1 + off; cobox[slot * 4 + 1] = y1 + off;
    cobox[slot * 4 + 2] = x2 + off; cobox[slot * 4 + 3] = y2 + off;
}

// ---------------- exact rank by counting (LDS-staged keys), scatter ----------------
__global__ __launch_bounds__(256) void k_rank(const u64* __restrict__ key64, const float* __restrict__ csc,
                       const float* __restrict__ cbox, const float* __restrict__ cobox,
                       float* __restrict__ ssc, float* __restrict__ sbox, float* __restrict__ sobox) {
    int n = blockIdx.y;
    __shared__ u64 kk[KTOT];                     // 40 KB
    for (int t = threadIdx.x; t < KTOT; t += 256) kk[t] = key64[(size_t)n * KTOT + t];
    __syncthreads();
    int i = blockIdx.x * 256 + threadIdx.x;
    if (i >= KTOT) return;
    u64 ki = kk[i];
    int rank = 0;
    for (int j = 0; j < KTOT; ++j) rank += (kk[j] > ki) ? 1 : 0;   // lockstep j -> LDS broadcast
    int src = n * KTOT + i, dst = n * KTOT + rank;
    ssc[dst] = csc[src];
    sbox[dst * 4 + 0] = cbox[src * 4 + 0]; sbox[dst * 4 + 1] = cbox[src * 4 + 1];
    sbox[dst * 4 + 2] = cbox[src * 4 + 2]; sbox[dst * 4 + 3] = cbox[src * 4 + 3];
    sobox[dst * 4 + 0] = cobox[src * 4 + 0]; sobox[dst * 4 + 1] = cobox[src * 4 + 1];
    sobox[dst * 4 + 2] = cobox[src * 4 + 2]; sobox[dst * 4 + 3] = cobox[src * 4 + 3];
}

// ---------------- IoU suppression bitmask matrix ----------------
__global__ void k_mask(const float* __restrict__ sobox, u64* __restrict__ mask) {
    int n = blockIdx.z;
    int i = blockIdx.x * 64 + threadIdx.x;
    int j0 = blockIdx.y * 64;
    __shared__ float cb[64][4];
    int jl = j0 + threadIdx.x;
    if (jl < KTOT) {
        cb[threadIdx.x][0] = sobox[(size_t)(n * KTOT + jl) * 4 + 0];
        cb[threadIdx.x][1] = sobox[(size_t)(n * KTOT + jl) * 4 + 1];
        cb[threadIdx.x][2] = sobox[(size_t)(n * KTOT + jl) * 4 + 2];
        cb[threadIdx.x][3] = sobox[(size_t)(n * KTOT + jl) * 4 + 3];
    } else {
        cb[threadIdx.x][0] = 0.f; cb[threadIdx.x][1] = 0.f;
        cb[threadIdx.x][2] = 0.f; cb[threadIdx.x][3] = 0.f;
    }
    __syncthreads();
    if (i >= KTOT) return;
    float x1 = sobox[(size_t)(n * KTOT + i) * 4 + 0];
    float y1 = sobox[(size_t)(n * KTOT + i) * 4 + 1];
    float x2 = sobox[(size_t)(n * KTOT + i) * 4 + 2];
    float y2 = sobox[(size_t)(n * KTOT + i) * 4 + 3];
    float areai = fmaxf(x2 - x1, 0.f) * fmaxf(y2 - y1, 0.f);
    u64 bits = 0;
    int lim = KTOT - j0; if (lim > 64) lim = 64;
    for (int jj = 0; jj < lim; ++jj) {
        float bx1 = cb[jj][0], by1 = cb[jj][1], bx2 = cb[jj][2], by2 = cb[jj][3];
        float areaj = fmaxf(bx2 - bx1, 0.f) * fmaxf(by2 - by1, 0.f);
        float ltx = fmaxf(x1, bx1), lty = fmaxf(y1, by1);
        float rbx = fminf(x2, bx2), rby = fminf(y2, by2);
        float iw = fmaxf(rbx - ltx, 0.f), ih = fmaxf(rby - lty, 0.f);
        float inter = iw * ih;
        float iou = inter / (areai + areaj - inter + 1e-9f);
        if (iou > 0.7f) bits |= (1ULL << jj);
    }
    mask[(size_t)(n * KTOT + i) * MASK_STRIDE + blockIdx.y] = bits;
}

// ---------------- batched greedy NMS: 512-thread cooperative row staging ----------------
// Exact greedy: per batch, wave 0 gathers the next BATCH alive candidates in rank
// order; ALL 512 threads stage the BATCH mask rows to LDS with plain coalesced
// loads (5120 independent dwordx2 -> one memory latency); wave 0 builds 64x64
// suppression columns and runs the serial closure in registers (identical to
// sequential greedy); union + cursor advance cooperative.
__global__ __launch_bounds__(512, 1) void k_nms(const float* __restrict__ ssc,
                      const float* __restrict__ sbox,
                      const u64* __restrict__ mask, float* __restrict__ out) {
    int n = blockIdx.x, tid = threadIdx.x;
    int lane = tid & 63, wv = tid >> 6;
    __shared__ u64 rows[BATCH][MASK_STRIDE];     // 40 KB staging
    __shared__ u64 rem[MASK_STRIDE];             // bit set = dead
    __shared__ int lst[BATCH];
    __shared__ u64 cmS;
    __shared__ int havS, picksS, curS;

    // dead-map init: wave w handles words w, w+8, ... (parallel ballots)
    for (int c = wv; c < 79; c += 8) {
        int i = c * 64 + lane;
        bool dead = (i >= KTOT) || !(ssc[n * KTOT + i] > -INFINITY);
        u64 db = __ballot(dead);
        if (lane == 0) rem[c] = db;
    }
    if (tid == 0) { rem[79] = ~0ULL; picksS = 0; curS = 0; }
    __syncthreads();

    while (true) {
        int picks = picksS, cur = curS;          // consistent: read right after barrier
        if (picks >= 1000 || cur >= 79) break;

        // ---- wave 0: gather next BATCH alive candidates (ascending rank) ----
        if (wv == 0) {
            int have = 0, scanw = cur;
            while (have < BATCH && scanw < 79) {
                int wi = scanw + lane;
                u64 alive = (wi < 79) ? ~rem[wi] : 0ULL;
                int pc = __popcll(alive);
                int inc = pc;
                #pragma unroll
                for (int off = 1; off < 64; off <<= 1) {
                    int v = __shfl_up(inc, off);
                    if (lane >= off) inc += v;
                }
                int excl = have + inc - pc;
                u64 a = alive; int t = 0;
                while (a && (excl + t) < BATCH) {
                    int b = __ffsll(a) - 1;
                    lst[excl + t] = wi * 64 + b;
                    a &= a - 1; ++t;
                }
                int tot = __shfl(inc, 63);
                have += tot; if (have > BATCH) have = BATCH;
                scanw += 64;
            }
            if (lane == 0) havS = have;
        }
        __syncthreads();
        int batchN = havS;
        if (batchN == 0) break;

        // ---- cooperative row staging: 512 threads, plain coalesced loads ----
        for (int idx = tid; idx < batchN * MASK_STRIDE; idx += 512) {
            int d = idx / MASK_STRIDE, w = idx - d * MASK_STRIDE;
            rows[d][w] = mask[(size_t)(n * KTOT + lst[d]) * MASK_STRIDE + w];
        }
        __syncthreads();

        // ---- wave 0: suppression columns + serial greedy closure ----
        if (wv == 0) {
            u64 col = 0;
            if (lane < batchN) {
                int cd = lst[lane], wd = cd >> 6, bd = cd & 63;
                for (int e = 0; e < batchN; ++e)
                    col |= ((rows[e][wd] >> bd) & 1ULL) << e;
            }
            u64 cm = 0;
            for (int e = 0; e < batchN; ++e) {
                u64 ce = __shfl(col, e);
                if ((cm & ce) == 0ULL) cm |= (1ULL << e);
            }
            int allowed = 1000 - picks;
            int ncom = __popcll(cm);
            while (ncom > allowed) { cm &= ~(1ULL << (63 - __clzll(cm))); --ncom; }
            if (lane == 0) { cmS = cm; picksS = picks + ncom; }
            // outputs: lane d writes its committed candidate
            if (lane < batchN && ((cm >> lane) & 1ULL)) {
                int c = lst[lane];
                int pos = picks + (int)__popcll(cm & ((1ULL << lane) - 1ULL));
                const float* bp = &sbox[(size_t)(n * KTOT + c) * 4];
                float* op = &out[(n * 1000 + pos) * 5];
                op[0] = bp[0]; op[1] = bp[1]; op[2] = bp[2]; op[3] = bp[3];
                op[4] = ssc[n * KTOT + c];
            }
        }
        __syncthreads();

        // ---- union committed rows -> dead map (80 threads, one word each) ----
        u64 cm = cmS;
        if (tid < 80) {
            u64 s = rem[tid];
            for (int e = 0; e < batchN; ++e)
                if ((cm >> e) & 1ULL) s |= rows[e][tid];
            rem[tid] = s;
        }
        __syncthreads();

        // ---- advance cursor (wave 0) ----
        if (wv == 0) {
            u64 winAlive = ((cur + lane) < 79) ? ~rem[cur + lane] : 0ULL;
            u64 bal = __ballot(winAlive != 0ULL);
            int nc = (bal == 0ULL) ? cur + 64 : cur + __ffsll(bal) - 1;
            if (lane == 0) curS = nc;
        }
        __syncthreads();
    }
    __syncthreads();
    // zero-fill remaining output rows (reference emits zeros for invalid picks)
    int picksF = picksS;
    int basec = (n * 1000 + picksF) * 5, cnt = (1000 - picksF) * 5;
    for (int t = tid; t < cnt; t += 512) out[basec + t] = 0.f;
}

// ---------------- workspace layout ----------------
constexpr size_t OFF_MASK   = 0;
constexpr size_t SZ_MASK    = (size_t)NIMG * KTOT * MASK_STRIDE * 8;   // 6,400,000
constexpr size_t OFF_HIST   = OFF_MASK + SZ_MASK;                      // zeroed region start
constexpr size_t OFF_GCNT   = OFF_HIST + 10 * BINS * 4;
constexpr size_t OFF_ECNT   = OFF_GCNT + 64;
constexpr size_t ZERO_WORDS = (10 * BINS * 4 + 128) / 4;               // hist + gcnt + ecnt
constexpr size_t OFF_BINB   = OFF_ECNT + 64;
constexpr size_t OFF_KNEED  = OFF_BINB + 64;
constexpr size_t OFF_G0     = OFF_KNEED + 64;
constexpr size_t OFF_SEL    = OFF_G0 + 64;
constexpr size_t OFF_EQ     = OFF_SEL + 10 * K_PER_LVL * 4;            // 8-aligned
constexpr size_t OFF_KEY64  = OFF_EQ + (size_t)10 * EQ_CAP * 8;
constexpr size_t OFF_CSC    = OFF_KEY64 + (size_t)NIMG * KTOT * 8;
constexpr size_t OFF_CBOX   = OFF_CSC + (size_t)NIMG * KTOT * 4;
constexpr size_t OFF_COBOX  = OFF_CBOX + (size_t)NIMG * KTOT * 16;
constexpr size_t OFF_SSC    = OFF_COBOX + (size_t)NIMG * KTOT * 16;
constexpr size_t OFF_SBOX   = OFF_SSC + (size_t)NIMG * KTOT * 4;
constexpr size_t OFF_SOBOX  = OFF_SBOX + (size_t)NIMG * KTOT * 16;
constexpr size_t WS_NEEDED  = OFF_SOBOX + (size_t)NIMG * KTOT * 16;    // ~7.5 MB

extern "C" void kernel_launch(void* const* d_in, const int* in_sizes, int n_in,
                              void* d_out, int out_size, void* d_ws, size_t ws_size,
                              hipStream_t stream) {
    if (ws_size < WS_NEEDED) return;

    // Detect input ordering from sizes: dict order interleaves (obj0,box0,...)
    bool dictOrder = (in_sizes[1] > in_sizes[0]);
    Ptrs P;
    for (int l = 0; l < 5; ++l) {
        P.o[l] = (const float*)d_in[dictOrder ? (2 * l)     : l];
        P.b[l] = (const float*)d_in[dictOrder ? (2 * l + 1) : (5 + l)];
    }
    char* ws = (char*)d_ws;
    u64*   mask   = (u64*)(ws + OFF_MASK);
    u32*   hist   = (u32*)(ws + OFF_HIST);
    u32*   gcnt   = (u32*)(ws + OFF_GCNT);
    u32*   ecnt   = (u32*)(ws + OFF_ECNT);
    int*   binB   = (int*)(ws + OFF_BINB);
    int*   kneed  = (int*)(ws + OFF_KNEED);
    int*   g0     = (int*)(ws + OFF_G0);
    int*   sel    = (int*)(ws + OFF_SEL);
    u64*   eq     = (u64*)(ws + OFF_EQ);
    u64*   key64  = (u64*)(ws + OFF_KEY64);
    float* csc    = (float*)(ws + OFF_CSC);
    float* cbox   = (float*)(ws + OFF_CBOX);
    float* cobox  = (float*)(ws + OFF_COBOX);
    float* ssc    = (float*)(ws + OFF_SSC);
    float* sbox   = (float*)(ws + OFF_SBOX);
    float* sobox  = (float*)(ws + OFF_SOBOX);
    float* out    = (float*)d_out;

    k_zero<<<dim3(21), 256, 0, stream>>>(hist, (int)ZERO_WORDS);       // hist + gcnt + ecnt
    k_hist<<<dim3(32, 10), 256, 0, stream>>>(P, hist);
    k_resolve<<<10, 256, 0, stream>>>(hist, binB, kneed, g0);
    k_compact<<<dim3(64, 10), 256, 0, stream>>>(P, binB, gcnt, ecnt, sel, eq);
    k_eqsel<<<10, 256, 0, stream>>>(ecnt, kneed, g0, eq, sel);
    k_feat<<<dim3((NIMG * KTOT + 255) / 256), 256, 0, stream>>>(P, sel, key64, csc, cbox, cobox);
    k_rank<<<dim3((KTOT + 255) / 256, NIMG), 256, 0, stream>>>(key64, csc, cbox, cobox, ssc, sbox, sobox);
    k_mask<<<dim3(79, 79, NIMG), 64, 0, stream>>>(sobox, mask);
    k_nms<<<NIMG, 512, 0, stream>>>(ssc, sbox, mask, out);
}

// Round 8
// 342.724 us; speedup vs baseline: 2.8539x; 1.7317x over previous
//
#include <hip/hip_runtime.h>
#include <cmath>

#pragma clang fp contract(off)

typedef unsigned int u32;
typedef unsigned short u16;
typedef unsigned long long u64;

#define K_PER_LVL 1000
#define KTOT 5000            // 5 levels * 1000
#define NIMG 2
#define BINS 2048            // histogram bins = top 11 bits of fkey
#define BIN_SHIFT 21
#define EQ_CAP 2048
#define ECAP 32768           // max suppression edges per image (est ~4k; 8x margin)
#define LECAP 24576          // edges held in LDS; overflow spills to global

__constant__ int c_LG[5] = {512, 256, 128, 64, 32};      // grid dim (square)
__constant__ int c_LS[5] = {4, 8, 16, 32, 64};           // stride
__constant__ int c_LZ[5] = {32, 64, 128, 256, 512};      // anchor size
__constant__ int c_LM[5] = {786432, 196608, 49152, 12288, 3072}; // 3*G*G

struct Ptrs { const float* o[5]; const float* b[5]; };

// monotone float -> uint key (larger float => larger key)
__device__ inline u32 fkey(float f) {
    u32 u = __float_as_uint(f);
    return (u & 0x80000000u) ? ~u : (u | 0x80000000u);
}

// ---------------- zero hist + counters ----------------
__global__ __launch_bounds__(256) void k_zero(u32* __restrict__ z, int nwords) {
    int i = blockIdx.x * 256 + threadIdx.x;
    int stride = gridDim.x * 256;
    for (; i < nwords; i += stride) z[i] = 0;
}

// ---------------- one-pass 2048-bin histogram (float4 loads, LDS pre-agg) ----------------
__global__ __launch_bounds__(256) void k_hist(Ptrs P, u32* __restrict__ hist) {
    int p = blockIdx.y; int l = p % 5; int n = p / 5;
    int M4 = c_LM[l] >> 2;
    const float4* base = (const float4*)(P.o[l] + (size_t)n * c_LM[l]);
    __shared__ u32 lh[BINS];
    for (int i = threadIdx.x; i < BINS; i += 256) lh[i] = 0;
    __syncthreads();
    int stride = gridDim.x * 256;
    for (int i = blockIdx.x * 256 + threadIdx.x; i < M4; i += stride) {
        float4 v = base[i];
        atomicAdd(&lh[fkey(v.x) >> BIN_SHIFT], 1u);
        atomicAdd(&lh[fkey(v.y) >> BIN_SHIFT], 1u);
        atomicAdd(&lh[fkey(v.z) >> BIN_SHIFT], 1u);
        atomicAdd(&lh[fkey(v.w) >> BIN_SHIFT], 1u);
    }
    __syncthreads();
    for (int i = threadIdx.x; i < BINS; i += 256) {
        u32 c = lh[i];
        if (c) atomicAdd(&hist[p * BINS + i], c);
    }
}

// ---------------- resolve: threshold bin B, G = #(keys above B), KF = 1000 - G ----------------
__global__ __launch_bounds__(256) void k_resolve(const u32* __restrict__ hist,
                                                 int* __restrict__ binB, int* __restrict__ kneed,
                                                 int* __restrict__ g0) {
    int p = blockIdx.x, t = threadIdx.x;
    __shared__ u32 lh[BINS];
    __shared__ u32 seg[256];
    for (int i = t; i < BINS; i += 256) lh[i] = hist[p * BINS + i];
    __syncthreads();
    u32 s = 0;
    for (int q = 0; q < 8; ++q) s += lh[t * 8 + q];
    seg[t] = s;
    __syncthreads();
    if (t == 0) {
        u32 G = 0; int B = 0;
        for (int sg = 255; sg >= 0; --sg) {
            if (G + seg[sg] >= (u32)K_PER_LVL) {
                for (int b = sg * 8 + 7; b >= sg * 8; --b) {
                    u32 c = lh[b];
                    if (G + c >= (u32)K_PER_LVL) { B = b; break; }
                    G += c;
                }
                break;
            }
            G += seg[sg];
        }
        binB[p] = B;
        kneed[p] = K_PER_LVL - (int)G;   // KF taken from boundary bin
        g0[p] = (int)G;                  // count strictly above bin B
    }
}

// ---------------- compact: bin>B -> sel front; bin==B -> eq (packed key|~m) ----------------
__global__ __launch_bounds__(256) void k_compact(Ptrs P, const int* __restrict__ binB,
                                                 u32* gcnt, u32* ecnt,
                                                 int* __restrict__ sel, u64* __restrict__ eq) {
    int p = blockIdx.y; int l = p % 5; int n = p / 5;
    int M4 = c_LM[l] >> 2; int gg = c_LM[l] / 3;
    const float4* base = (const float4*)(P.o[l] + (size_t)n * c_LM[l]);
    int B = binB[p];
    int stride = gridDim.x * 256;
    for (int i4 = blockIdx.x * 256 + threadIdx.x; i4 < M4; i4 += stride) {
        float4 v = base[i4];
        float vv[4] = {v.x, v.y, v.z, v.w};
        #pragma unroll
        for (int q = 0; q < 4; ++q) {
            u32 k = fkey(vv[q]);
            int bin = (int)(k >> BIN_SHIFT);
            if (bin < B) continue;
            int i = i4 * 4 + q;
            // input linear i = a*gg + pix ; flattened m = pix*3 + a  (h,w,a order)
            int a = i / gg; int pix = i - a * gg; int m = pix * 3 + a;
            if (bin > B) {
                u32 pos = atomicAdd(&gcnt[p], 1u);
                sel[p * K_PER_LVL + pos] = m;
            } else {
                u32 e = atomicAdd(&ecnt[p], 1u);
                if (e < EQ_CAP) eq[(size_t)p * EQ_CAP + e] = ((u64)k << 20) | (u64)(0xFFFFFu ^ (u32)m);
            }
        }
    }
}

// ---------------- boundary bin: exact order (key desc, m asc) via LDS bitonic, take KF ----------------
__global__ __launch_bounds__(256) void k_eqsel(const u32* __restrict__ ecnt, const int* __restrict__ kneed,
                                               const int* __restrict__ g0,
                                               const u64* __restrict__ eq, int* __restrict__ sel) {
    int p = blockIdx.x, t = threadIdx.x;
    int E = (int)ecnt[p]; if (E > EQ_CAP) E = EQ_CAP;
    int KF = kneed[p]; int G0 = g0[p];
    __shared__ u64 a[EQ_CAP];
    for (int i = t; i < EQ_CAP; i += 256) a[i] = (i < E) ? eq[(size_t)p * EQ_CAP + i] : 0ULL;
    __syncthreads();
    for (int k = 2; k <= EQ_CAP; k <<= 1) {
        for (int j = k >> 1; j > 0; j >>= 1) {
            for (int i = t; i < EQ_CAP; i += 256) {
                int x = i ^ j;
                if (x > i) {
                    u64 va = a[i], vb = a[x];
                    bool up = (i & k) == 0;                 // descending sort
                    bool sw = up ? (va < vb) : (va > vb);
                    if (sw) { a[i] = vb; a[x] = va; }
                }
            }
            __syncthreads();
        }
    }
    for (int r = t; r < KF; r += 256) {
        int m = (int)(0xFFFFFu ^ (u32)(a[r] & 0xFFFFFu));
        sel[p * K_PER_LVL + G0 + r] = m;
    }
}

// ---------------- featurize: anchors + decode + clip + score + 64b order key ----------------
__global__ void k_feat(Ptrs P, const int* __restrict__ sel, u64* __restrict__ key64,
                       float* __restrict__ csc, float* __restrict__ cbox, float* __restrict__ cobox) {
    int tid = blockIdx.x * 256 + threadIdx.x;
    if (tid >= NIMG * KTOT) return;
    int p = tid / K_PER_LVL, s = tid - p * K_PER_LVL;
    int n = p / 5, l = p % 5;
    int G = c_LG[l], S = c_LS[l], Z = c_LZ[l];
    int gg = G * G;
    int m = sel[p * K_PER_LVL + s];
    int a = m % 3; int pix = m / 3; int h = pix / G; int w = pix - h * G;

    // anchor base: hr=sqrt(ar), wr=1/hr, round-half-even (matches jnp f32)
    const float ars[3] = {0.5f, 1.0f, 2.0f};
    float ar = ars[a];
    float hr = sqrtf(ar), wr = 1.0f / hr;
    float wsz = wr * (float)Z, hsz = hr * (float)Z;
    float bx1 = rintf(-0.5f * wsz), by1 = rintf(-0.5f * hsz);
    float bx2 = rintf(0.5f * wsz),  by2 = rintf(0.5f * hsz);
    float sx = (float)(w * S), sy = (float)(h * S);
    float ax1 = sx + bx1, ay1 = sy + by1, ax2 = sx + bx2, ay2 = sy + by2;
    float wa = ax2 - ax1, ha = ay2 - ay1;
    float cxa = ax1 + 0.5f * wa, cya = ay1 + 0.5f * ha;

    const float* bb = P.b[l] + (size_t)n * 12 * gg;
    float dx = bb[(a * 4 + 0) * gg + pix];
    float dy = bb[(a * 4 + 1) * gg + pix];
    const float CLIPV = 4.135166556742356f;  // log(1000/16)
    float dw = fminf(bb[(a * 4 + 2) * gg + pix], CLIPV);
    float dh = fminf(bb[(a * 4 + 3) * gg + pix], CLIPV);
    float cx = dx * wa + cxa, cy = dy * ha + cya;
    float ww = expf(dw) * wa, hh = expf(dh) * ha;
    float x1 = cx - 0.5f * ww, y1 = cy - 0.5f * hh;
    float x2 = cx + 0.5f * ww, y2 = cy + 0.5f * hh;
    x1 = fminf(fmaxf(x1, 0.f), 2048.f);
    y1 = fminf(fmaxf(y1, 0.f), 2048.f);
    x2 = fminf(fmaxf(x2, 0.f), 2048.f);
    y2 = fminf(fmaxf(y2, 0.f), 2048.f);

    float raw = P.o[l][(size_t)n * 3 * gg + a * gg + pix];
    float sc = 1.0f / (1.0f + expf(-raw));
    bool keep = (x2 - x1 >= 1e-3f) && (y2 - y1 >= 1e-3f) && (sc > 0.0f);

    int slot = n * KTOT + l * K_PER_LVL + s;
    // total order key: raw desc, then (level asc, m asc) == reference concat-position order
    u32 tb = ((u32)l << 20) | (u32)m;          // m < 2^20, l < 8  -> 23 bits, unique
    u32 kk = keep ? fkey(raw) : 0u;            // invalid sinks below every valid (finite raw)
    key64[slot] = ((u64)kk << 23) | (u64)(tb ^ 0x7FFFFFu);

    csc[slot] = keep ? sc : -INFINITY;
    cbox[slot * 4 + 0] = x1; cbox[slot * 4 + 1] = y1;
    cbox[slot * 4 + 2] = x2; cbox[slot * 4 + 3] = y2;
    float off = 4097.0f * (float)l;            // lvl * (W+H+1), batched_nms offset
    cobox[slot * 4 + 0] = x1 + off; cobox[slot * 4 + 1] = y1 + off;
    cobox[slot * 4 + 2] = x2 + off; cobox[slot * 4 + 3] = y2 + off;
}

// ---------------- exact rank by counting (LDS-staged keys), scatter ----------------
__global__ __launch_bounds__(256) void k_rank(const u64* __restrict__ key64, const float* __restrict__ csc,
                       const float* __restrict__ cbox, const float* __restrict__ cobox,
                       float* __restrict__ ssc, float* __restrict__ sbox, float* __restrict__ sobox) {
    int n = blockIdx.y;
    __shared__ u64 kk[KTOT];                     // 40 KB
    for (int t = threadIdx.x; t < KTOT; t += 256) kk[t] = key64[(size_t)n * KTOT + t];
    __syncthreads();
    int i = blockIdx.x * 256 + threadIdx.x;
    if (i >= KTOT) return;
    u64 ki = kk[i];
    int rank = 0;
    for (int j = 0; j < KTOT; ++j) rank += (kk[j] > ki) ? 1 : 0;   // lockstep j -> LDS broadcast
    int src = n * KTOT + i, dst = n * KTOT + rank;
    ssc[dst] = csc[src];
    sbox[dst * 4 + 0] = cbox[src * 4 + 0]; sbox[dst * 4 + 1] = cbox[src * 4 + 1];
    sbox[dst * 4 + 2] = cbox[src * 4 + 2]; sbox[dst * 4 + 3] = cbox[src * 4 + 3];
    sobox[dst * 4 + 0] = cobox[src * 4 + 0]; sobox[dst * 4 + 1] = cobox[src * 4 + 1];
    sobox[dst * 4 + 2] = cobox[src * 4 + 2]; sobox[dst * 4 + 3] = cobox[src * 4 + 3];
}

// ---------------- sparse suppression edges: forward pairs (i<j) with IoU>0.7 ----------------
// IoU arithmetic identical to the previously-verified dense k_mask.
__global__ void k_edge(const float* __restrict__ sobox, u32* __restrict__ gE, u32* __restrict__ gPairs) {
    int n = blockIdx.z;
    int bi = blockIdx.x, bj = blockIdx.y;
    if (bj < bi) return;                         // forward-only (upper triangle)
    int i = bi * 64 + threadIdx.x;
    int j0 = bj * 64;
    __shared__ float cb[64][4];
    int jl = j0 + threadIdx.x;
    if (jl < KTOT) {
        cb[threadIdx.x][0] = sobox[(size_t)(n * KTOT + jl) * 4 + 0];
        cb[threadIdx.x][1] = sobox[(size_t)(n * KTOT + jl) * 4 + 1];
        cb[threadIdx.x][2] = sobox[(size_t)(n * KTOT + jl) * 4 + 2];
        cb[threadIdx.x][3] = sobox[(size_t)(n * KTOT + jl) * 4 + 3];
    } else {
        cb[threadIdx.x][0] = 0.f; cb[threadIdx.x][1] = 0.f;
        cb[threadIdx.x][2] = 0.f; cb[threadIdx.x][3] = 0.f;
    }
    __syncthreads();
    if (i >= KTOT) return;
    float x1 = sobox[(size_t)(n * KTOT + i) * 4 + 0];
    float y1 = sobox[(size_t)(n * KTOT + i) * 4 + 1];
    float x2 = sobox[(size_t)(n * KTOT + i) * 4 + 2];
    float y2 = sobox[(size_t)(n * KTOT + i) * 4 + 3];
    float areai = fmaxf(x2 - x1, 0.f) * fmaxf(y2 - y1, 0.f);
    int lim = KTOT - j0; if (lim > 64) lim = 64;
    for (int jj = 0; jj < lim; ++jj) {
        int j = j0 + jj;
        if (j <= i) continue;
        float bx1 = cb[jj][0], by1 = cb[jj][1], bx2 = cb[jj][2], by2 = cb[jj][3];
        float areaj = fmaxf(bx2 - bx1, 0.f) * fmaxf(by2 - by1, 0.f);
        float ltx = fmaxf(x1, bx1), lty = fmaxf(y1, by1);
        float rbx = fminf(x2, bx2), rby = fminf(y2, by2);
        float iw = fmaxf(rbx - ltx, 0.f), ih = fmaxf(rby - lty, 0.f);
        float inter = iw * ih;
        float iou = inter / (areai + areaj - inter + 1e-9f);
        if (iou > 0.7f) {
            u32 pos = atomicAdd(&gE[n], 1u);
            if (pos < ECAP) gPairs[(size_t)n * ECAP + pos] = ((u32)i << 13) | (u32)j;
        }
    }
}

// ---------------- greedy NMS sweep over sparse CSR (zero global mem on sweep path) ----------------
__global__ __launch_bounds__(256, 1) void k_nms(const float* __restrict__ ssc,
                      const float* __restrict__ sbox,
                      const u32* __restrict__ gE, const u32* __restrict__ gPairs,
                      u16* __restrict__ gEdges, float* __restrict__ out) {
    int n = blockIdx.x, tid = threadIdx.x;
    int lane = tid & 63, wv = tid >> 6;          // 4 waves
    __shared__ u32 cnt[KTOT];                    // 20 KB (count, then fill cursor)
    __shared__ u32 offs[KTOT + 1];               // 20 KB
    __shared__ u16 edges[LECAP];                 // 48 KB
    __shared__ u32 rem32[160];                   // dead bitmap (2 u32 per 64-word)
    __shared__ u32 colLo[64], colHi[64];
    __shared__ u32 scanb[256];
    __shared__ int picksS;

    // zero cnt + rem tail
    for (int i = tid; i < KTOT; i += 256) cnt[i] = 0;
    if (tid < 160) rem32[tid] = 0xFFFFFFFFu;     // default dead; real words overwritten
    __syncthreads();
    // dead-map init from scores (wave-parallel ballots)
    for (int w = wv; w < 79; w += 4) {
        int i = w * 64 + lane;
        bool dead = (i >= KTOT) || !(ssc[n * KTOT + i] > -INFINITY);
        u64 db = __ballot(dead);
        if (lane == 0) { rem32[2 * w] = (u32)db; rem32[2 * w + 1] = (u32)(db >> 32); }
    }
    __syncthreads();

    // ---- CSR build from global pair list ----
    int E = (int)gE[n]; if (E > ECAP) E = ECAP;
    for (int k = tid; k < E; k += 256) {
        u32 p = gPairs[(size_t)n * ECAP + k];
        atomicAdd(&cnt[p >> 13], 1u);
    }
    __syncthreads();
    // scan: 250 threads x 20 elems + block Hillis-Steele over totals
    u32 s = 0; int base = tid * 20;
    if (tid < 250) for (int q = 0; q < 20; ++q) s += cnt[base + q];
    scanb[tid] = s;
    __syncthreads();
    for (int off = 1; off < 256; off <<= 1) {
        u32 v = (tid >= off) ? scanb[tid - off] : 0;
        __syncthreads();
        scanb[tid] += v;
        __syncthreads();
    }
    u32 tbase = (tid == 0) ? 0u : scanb[tid - 1];
    if (tid < 250) {
        u32 run = tbase;
        for (int q = 0; q < 20; ++q) { offs[base + q] = run; run += cnt[base + q]; }
    }
    if (tid == 0) offs[KTOT] = scanb[255];
    __syncthreads();
    for (int i = tid; i < KTOT; i += 256) cnt[i] = 0;   // reuse as fill cursor
    __syncthreads();
    for (int k = tid; k < E; k += 256) {
        u32 p = gPairs[(size_t)n * ECAP + k];
        u32 src = p >> 13, dst = p & 0x1FFFu;
        u32 slot = offs[src] + atomicAdd(&cnt[src], 1u);
        if (slot < LECAP) edges[slot] = (u16)dst;
        else gEdges[(size_t)n * ECAP + slot] = (u16)dst;
    }
    __syncthreads();

    // ---- wave-0 sweep: rank order, no global memory on the critical path ----
    if (wv == 0) {
        int picks = 0;
        for (int w = 0; w < 79 && picks < 1000; ++w) {
            u64 rw = ((u64)rem32[2 * w + 1] << 32) | rem32[2 * w];
            u64 alive = ~rw;
            if (alive == 0ULL) continue;
            int c = w * 64 + lane;
            bool amAlive = ((alive >> lane) & 1ULL) != 0ULL;
            int e0 = 0, e1 = 0;
            if (amAlive) { e0 = (int)offs[c]; e1 = (int)offs[c + 1]; }
            // intra-word suppression bits (rare)
            colLo[lane] = 0; colHi[lane] = 0;
            bool anyIntra = false;
            for (int k = e0; k < e1; ++k) {
                int dst = (k < LECAP) ? (int)edges[k] : (int)gEdges[(size_t)n * ECAP + k];
                if ((dst >> 6) == w) {
                    if (lane < 32) atomicOr(&colLo[dst & 63], 1u << lane);
                    else           atomicOr(&colHi[dst & 63], 1u << (lane - 32));
                    anyIntra = true;
                }
            }
            u64 cm;
            if (__ballot(anyIntra) == 0ULL) {
                cm = alive;                                   // fast path: no intra-word conflicts
            } else {
                u64 col = ((u64)colHi[lane] << 32) | colLo[lane];
                cm = 0ULL;
                for (int e = 0; e < 64; ++e) {
                    if (!((alive >> e) & 1ULL)) continue;
                    u64 ce = __shfl(col, e);
                    if ((cm & ce) == 0ULL) cm |= (1ULL << e);
                }
            }
            int allowed = 1000 - picks;
            int ncom = __popcll(cm);
            while (ncom > allowed) { cm &= ~(1ULL << (63 - __clzll(cm))); --ncom; }
            // committed lanes: write output + apply forward kills
            if ((cm >> lane) & 1ULL) {
                int pos = picks + (int)__popcll(cm & ((1ULL << lane) - 1ULL));
                const float* bp = &sbox[(size_t)(n * KTOT + c) * 4];
                float* op = &out[(n * 1000 + pos) * 5];
                op[0] = bp[0]; op[1] = bp[1]; op[2] = bp[2]; op[3] = bp[3];
                op[4] = ssc[n * KTOT + c];
                for (int k = e0; k < e1; ++k) {
                    int dst = (k < LECAP) ? (int)edges[k] : (int)gEdges[(size_t)n * ECAP + k];
                    atomicOr(&rem32[dst >> 5], 1u << (dst & 31));
                }
            }
            picks += ncom;
        }
        if (lane == 0) picksS = picks;
    }
    __syncthreads();
    // zero-fill remaining output rows
    int picksF = picksS;
    int basec = (n * 1000 + picksF) * 5, cntz = (1000 - picksF) * 5;
    for (int t = tid; t < cntz; t += 256) out[basec + t] = 0.f;
}

// ---------------- workspace layout ----------------
constexpr size_t OFF_HIST   = 0;                                       // zeroed region start
constexpr size_t OFF_GCNT   = OFF_HIST + 10 * BINS * 4;                // 81920
constexpr size_t OFF_ECNT   = OFF_GCNT + 64;
constexpr size_t OFF_GEC    = OFF_ECNT + 64;                           // edge counters (2 u32)
constexpr size_t ZERO_WORDS = (10 * BINS * 4 + 192) / 4;               // hist + gcnt + ecnt + gec
constexpr size_t OFF_BINB   = OFF_GEC + 64;
constexpr size_t OFF_KNEED  = OFF_BINB + 64;
constexpr size_t OFF_G0     = OFF_KNEED + 64;
constexpr size_t OFF_SEL    = OFF_G0 + 64;
constexpr size_t OFF_EQ     = OFF_SEL + 10 * K_PER_LVL * 4;            // 8-aligned
constexpr size_t OFF_KEY64  = OFF_EQ + (size_t)10 * EQ_CAP * 8;
constexpr size_t OFF_CSC    = OFF_KEY64 + (size_t)NIMG * KTOT * 8;
constexpr size_t OFF_CBOX   = OFF_CSC + (size_t)NIMG * KTOT * 4;
constexpr size_t OFF_COBOX  = OFF_CBOX + (size_t)NIMG * KTOT * 16;
constexpr size_t OFF_SSC    = OFF_COBOX + (size_t)NIMG * KTOT * 16;
constexpr size_t OFF_SBOX   = OFF_SSC + (size_t)NIMG * KTOT * 4;
constexpr size_t OFF_SOBOX  = OFF_SBOX + (size_t)NIMG * KTOT * 16;
constexpr size_t OFF_PAIRS  = OFF_SOBOX + (size_t)NIMG * KTOT * 16;    // u32[NIMG*ECAP]
constexpr size_t OFF_ESPILL = OFF_PAIRS + (size_t)NIMG * ECAP * 4;     // u16[NIMG*ECAP]
constexpr size_t WS_NEEDED  = OFF_ESPILL + (size_t)NIMG * ECAP * 2;    // ~2.3 MB

extern "C" void kernel_launch(void* const* d_in, const int* in_sizes, int n_in,
                              void* d_out, int out_size, void* d_ws, size_t ws_size,
                              hipStream_t stream) {
    if (ws_size < WS_NEEDED) return;

    // Detect input ordering from sizes: dict order interleaves (obj0,box0,...)
    bool dictOrder = (in_sizes[1] > in_sizes[0]);
    Ptrs P;
    for (int l = 0; l < 5; ++l) {
        P.o[l] = (const float*)d_in[dictOrder ? (2 * l)     : l];
        P.b[l] = (const float*)d_in[dictOrder ? (2 * l + 1) : (5 + l)];
    }
    char* ws = (char*)d_ws;
    u32*   hist   = (u32*)(ws + OFF_HIST);
    u32*   gcnt   = (u32*)(ws + OFF_GCNT);
    u32*   ecnt   = (u32*)(ws + OFF_ECNT);
    u32*   gec    = (u32*)(ws + OFF_GEC);
    int*   binB   = (int*)(ws + OFF_BINB);
    int*   kneed  = (int*)(ws + OFF_KNEED);
    int*   g0     = (int*)(ws + OFF_G0);
    int*   sel    = (int*)(ws + OFF_SEL);
    u64*   eq     = (u64*)(ws + OFF_EQ);
    u64*   key64  = (u64*)(ws + OFF_KEY64);
    float* csc    = (float*)(ws + OFF_CSC);
    float* cbox   = (float*)(ws + OFF_CBOX);
    float* cobox  = (float*)(ws + OFF_COBOX);
    float* ssc    = (float*)(ws + OFF_SSC);
    float* sbox   = (float*)(ws + OFF_SBOX);
    float* sobox  = (float*)(ws + OFF_SOBOX);
    u32*   pairs  = (u32*)(ws + OFF_PAIRS);
    u16*   espill = (u16*)(ws + OFF_ESPILL);
    float* out    = (float*)d_out;

    k_zero<<<dim3(21), 256, 0, stream>>>(hist, (int)ZERO_WORDS);       // hist + counters + edge counters
    k_hist<<<dim3(32, 10), 256, 0, stream>>>(P, hist);
    k_resolve<<<10, 256, 0, stream>>>(hist, binB, kneed, g0);
    k_compact<<<dim3(64, 10), 256, 0, stream>>>(P, binB, gcnt, ecnt, sel, eq);
    k_eqsel<<<10, 256, 0, stream>>>(ecnt, kneed, g0, eq, sel);
    k_feat<<<dim3((NIMG * KTOT + 255) / 256), 256, 0, stream>>>(P, sel, key64, csc, cbox, cobox);
    k_rank<<<dim3((KTOT + 255) / 256, NIMG), 256, 0, stream>>>(key64, csc, cbox, cobox, ssc, sbox, sobox);
    k_edge<<<dim3(79, 79, NIMG), 64, 0, stream>>>(sobox, gec, pairs);
    k_nms<<<NIMG, 256, 0, stream>>>(ssc, sbox, gec, pairs, espill, out);
}

// Round 9
// 331.254 us; speedup vs baseline: 2.9527x; 1.0346x over previous
//
#include <hip/hip_runtime.h>
#include <cmath>

#pragma clang fp contract(off)

typedef unsigned int u32;
typedef unsigned short u16;
typedef unsigned long long u64;

#define K_PER_LVL 1000
#define KTOT 5000            // 5 levels * 1000
#define NIMG 2
#define BINS 2048            // histogram bins = top 11 bits of fkey
#define BIN_SHIFT 21
#define EQ_CAP 2048
#define ECAP 32768           // max suppression edges per image (est ~4k; 8x margin)
#define LECAP 24576          // edges held in LDS; overflow spills to global

__constant__ int c_LG[5] = {512, 256, 128, 64, 32};      // grid dim (square)
__constant__ int c_LS[5] = {4, 8, 16, 32, 64};           // stride
__constant__ int c_LZ[5] = {32, 64, 128, 256, 512};      // anchor size
__constant__ int c_LM[5] = {786432, 196608, 49152, 12288, 3072}; // 3*G*G

struct Ptrs { const float* o[5]; const float* b[5]; };

// monotone float -> uint key (larger float => larger key)
__device__ inline u32 fkey(float f) {
    u32 u = __float_as_uint(f);
    return (u & 0x80000000u) ? ~u : (u | 0x80000000u);
}

// ---------------- zero hist + counters ----------------
__global__ __launch_bounds__(256) void k_zero(u32* __restrict__ z, int nwords) {
    int i = blockIdx.x * 256 + threadIdx.x;
    int stride = gridDim.x * 256;
    for (; i < nwords; i += stride) z[i] = 0;
}

// ---------------- one-pass 2048-bin histogram (float4 loads, LDS pre-agg) ----------------
__global__ __launch_bounds__(256) void k_hist(Ptrs P, u32* __restrict__ hist) {
    int p = blockIdx.y; int l = p % 5; int n = p / 5;
    int M4 = c_LM[l] >> 2;
    const float4* base = (const float4*)(P.o[l] + (size_t)n * c_LM[l]);
    __shared__ u32 lh[BINS];
    for (int i = threadIdx.x; i < BINS; i += 256) lh[i] = 0;
    __syncthreads();
    int stride = gridDim.x * 256;
    for (int i = blockIdx.x * 256 + threadIdx.x; i < M4; i += stride) {
        float4 v = base[i];
        atomicAdd(&lh[fkey(v.x) >> BIN_SHIFT], 1u);
        atomicAdd(&lh[fkey(v.y) >> BIN_SHIFT], 1u);
        atomicAdd(&lh[fkey(v.z) >> BIN_SHIFT], 1u);
        atomicAdd(&lh[fkey(v.w) >> BIN_SHIFT], 1u);
    }
    __syncthreads();
    for (int i = threadIdx.x; i < BINS; i += 256) {
        u32 c = lh[i];
        if (c) atomicAdd(&hist[p * BINS + i], c);
    }
}

// ---------------- resolve: threshold bin B, G = #(keys above B), KF = 1000 - G ----------------
__global__ __launch_bounds__(256) void k_resolve(const u32* __restrict__ hist,
                                                 int* __restrict__ binB, int* __restrict__ kneed,
                                                 int* __restrict__ g0) {
    int p = blockIdx.x, t = threadIdx.x;
    __shared__ u32 lh[BINS];
    __shared__ u32 seg[256];
    for (int i = t; i < BINS; i += 256) lh[i] = hist[p * BINS + i];
    __syncthreads();
    u32 s = 0;
    for (int q = 0; q < 8; ++q) s += lh[t * 8 + q];
    seg[t] = s;
    __syncthreads();
    if (t == 0) {
        u32 G = 0; int B = 0;
        for (int sg = 255; sg >= 0; --sg) {
            if (G + seg[sg] >= (u32)K_PER_LVL) {
                for (int b = sg * 8 + 7; b >= sg * 8; --b) {
                    u32 c = lh[b];
                    if (G + c >= (u32)K_PER_LVL) { B = b; break; }
                    G += c;
                }
                break;
            }
            G += seg[sg];
        }
        binB[p] = B;
        kneed[p] = K_PER_LVL - (int)G;   // KF taken from boundary bin
        g0[p] = (int)G;                  // count strictly above bin B
    }
}

// ---------------- compact: bin>B -> sel front; bin==B -> eq (packed key|~m) ----------------
__global__ __launch_bounds__(256) void k_compact(Ptrs P, const int* __restrict__ binB,
                                                 u32* gcnt, u32* ecnt,
                                                 int* __restrict__ sel, u64* __restrict__ eq) {
    int p = blockIdx.y; int l = p % 5; int n = p / 5;
    int M4 = c_LM[l] >> 2; int gg = c_LM[l] / 3;
    const float4* base = (const float4*)(P.o[l] + (size_t)n * c_LM[l]);
    int B = binB[p];
    int stride = gridDim.x * 256;
    for (int i4 = blockIdx.x * 256 + threadIdx.x; i4 < M4; i4 += stride) {
        float4 v = base[i4];
        float vv[4] = {v.x, v.y, v.z, v.w};
        #pragma unroll
        for (int q = 0; q < 4; ++q) {
            u32 k = fkey(vv[q]);
            int bin = (int)(k >> BIN_SHIFT);
            if (bin < B) continue;
            int i = i4 * 4 + q;
            // input linear i = a*gg + pix ; flattened m = pix*3 + a  (h,w,a order)
            int a = i / gg; int pix = i - a * gg; int m = pix * 3 + a;
            if (bin > B) {
                u32 pos = atomicAdd(&gcnt[p], 1u);
                sel[p * K_PER_LVL + pos] = m;
            } else {
                u32 e = atomicAdd(&ecnt[p], 1u);
                if (e < EQ_CAP) eq[(size_t)p * EQ_CAP + e] = ((u64)k << 20) | (u64)(0xFFFFFu ^ (u32)m);
            }
        }
    }
}

// ---------------- boundary bin: rank-by-count selection (keys unique), take KF lowest ranks ----------------
// Replaces the 2048-element bitonic sort (66 barrier phases, 67 us): one uniform
// j-loop over E (LDS broadcast) computing exact ranks; element with rank<KF goes
// to sel[G0+rank]. Bit-identical selection (rank == sorted position).
__global__ __launch_bounds__(256) void k_eqsel(const u32* __restrict__ ecnt, const int* __restrict__ kneed,
                                               const int* __restrict__ g0,
                                               const u64* __restrict__ eq, int* __restrict__ sel) {
    int p = blockIdx.x, t = threadIdx.x;
    int E = (int)ecnt[p]; if (E > EQ_CAP) E = EQ_CAP;
    int KF = kneed[p]; int G0 = g0[p];
    __shared__ u64 a[EQ_CAP];
    for (int i = t; i < E; i += 256) a[i] = eq[(size_t)p * EQ_CAP + i];
    __syncthreads();
    u64 mine[8]; int rk[8];
    #pragma unroll
    for (int q = 0; q < 8; ++q) {
        int i = t + q * 256;
        mine[q] = (i < E) ? a[i] : 0ULL;
        rk[q] = 0;
    }
    for (int j = 0; j < E; ++j) {
        u64 v = a[j];                            // uniform index -> LDS broadcast
        #pragma unroll
        for (int q = 0; q < 8; ++q) rk[q] += (v > mine[q]) ? 1 : 0;
    }
    #pragma unroll
    for (int q = 0; q < 8; ++q) {
        int i = t + q * 256;
        if (i < E && rk[q] < KF) {
            int m = (int)(0xFFFFFu ^ (u32)(mine[q] & 0xFFFFFu));
            sel[p * K_PER_LVL + G0 + rk[q]] = m;
        }
    }
}

// ---------------- featurize: anchors + decode + clip + score + 64b order key ----------------
__global__ void k_feat(Ptrs P, const int* __restrict__ sel, u64* __restrict__ key64,
                       float* __restrict__ csc, float* __restrict__ cbox, float* __restrict__ cobox) {
    int tid = blockIdx.x * 256 + threadIdx.x;
    if (tid >= NIMG * KTOT) return;
    int p = tid / K_PER_LVL, s = tid - p * K_PER_LVL;
    int n = p / 5, l = p % 5;
    int G = c_LG[l], S = c_LS[l], Z = c_LZ[l];
    int gg = G * G;
    int m = sel[p * K_PER_LVL + s];
    int a = m % 3; int pix = m / 3; int h = pix / G; int w = pix - h * G;

    // anchor base: hr=sqrt(ar), wr=1/hr, round-half-even (matches jnp f32)
    const float ars[3] = {0.5f, 1.0f, 2.0f};
    float ar = ars[a];
    float hr = sqrtf(ar), wr = 1.0f / hr;
    float wsz = wr * (float)Z, hsz = hr * (float)Z;
    float bx1 = rintf(-0.5f * wsz), by1 = rintf(-0.5f * hsz);
    float bx2 = rintf(0.5f * wsz),  by2 = rintf(0.5f * hsz);
    float sx = (float)(w * S), sy = (float)(h * S);
    float ax1 = sx + bx1, ay1 = sy + by1, ax2 = sx + bx2, ay2 = sy + by2;
    float wa = ax2 - ax1, ha = ay2 - ay1;
    float cxa = ax1 + 0.5f * wa, cya = ay1 + 0.5f * ha;

    const float* bb = P.b[l] + (size_t)n * 12 * gg;
    float dx = bb[(a * 4 + 0) * gg + pix];
    float dy = bb[(a * 4 + 1) * gg + pix];
    const float CLIPV = 4.135166556742356f;  // log(1000/16)
    float dw = fminf(bb[(a * 4 + 2) * gg + pix], CLIPV);
    float dh = fminf(bb[(a * 4 + 3) * gg + pix], CLIPV);
    float cx = dx * wa + cxa, cy = dy * ha + cya;
    float ww = expf(dw) * wa, hh = expf(dh) * ha;
    float x1 = cx - 0.5f * ww, y1 = cy - 0.5f * hh;
    float x2 = cx + 0.5f * ww, y2 = cy + 0.5f * hh;
    x1 = fminf(fmaxf(x1, 0.f), 2048.f);
    y1 = fminf(fmaxf(y1, 0.f), 2048.f);
    x2 = fminf(fmaxf(x2, 0.f), 2048.f);
    y2 = fminf(fmaxf(y2, 0.f), 2048.f);

    float raw = P.o[l][(size_t)n * 3 * gg + a * gg + pix];
    float sc = 1.0f / (1.0f + expf(-raw));
    bool keep = (x2 - x1 >= 1e-3f) && (y2 - y1 >= 1e-3f) && (sc > 0.0f);

    int slot = n * KTOT + l * K_PER_LVL + s;
    // total order key: raw desc, then (level asc, m asc) == reference concat-position order
    u32 tb = ((u32)l << 20) | (u32)m;          // m < 2^20, l < 8  -> 23 bits, unique
    u32 kk = keep ? fkey(raw) : 0u;            // invalid sinks below every valid (finite raw)
    key64[slot] = ((u64)kk << 23) | (u64)(tb ^ 0x7FFFFFu);

    csc[slot] = keep ? sc : -INFINITY;
    cbox[slot * 4 + 0] = x1; cbox[slot * 4 + 1] = y1;
    cbox[slot * 4 + 2] = x2; cbox[slot * 4 + 3] = y2;
    float off = 4097.0f * (float)l;            // lvl * (W+H+1), batched_nms offset
    cobox[slot * 4 + 0] = x1 + off; cobox[slot * 4 + 1] = y1 + off;
    cobox[slot * 4 + 2] = x2 + off; cobox[slot * 4 + 3] = y2 + off;
}

// ---------------- exact rank by counting (LDS-staged keys), scatter ----------------
__global__ __launch_bounds__(256) void k_rank(const u64* __restrict__ key64, const float* __restrict__ csc,
                       const float* __restrict__ cbox, const float* __restrict__ cobox,
                       float* __restrict__ ssc, float* __restrict__ sbox, float* __restrict__ sobox) {
    int n = blockIdx.y;
    __shared__ u64 kk[KTOT];                     // 40 KB
    for (int t = threadIdx.x; t < KTOT; t += 256) kk[t] = key64[(size_t)n * KTOT + t];
    __syncthreads();
    int i = blockIdx.x * 256 + threadIdx.x;
    if (i >= KTOT) return;
    u64 ki = kk[i];
    int rank = 0;
    for (int j = 0; j < KTOT; ++j) rank += (kk[j] > ki) ? 1 : 0;   // lockstep j -> LDS broadcast
    int src = n * KTOT + i, dst = n * KTOT + rank;
    ssc[dst] = csc[src];
    sbox[dst * 4 + 0] = cbox[src * 4 + 0]; sbox[dst * 4 + 1] = cbox[src * 4 + 1];
    sbox[dst * 4 + 2] = cbox[src * 4 + 2]; sbox[dst * 4 + 3] = cbox[src * 4 + 3];
    sobox[dst * 4 + 0] = cobox[src * 4 + 0]; sobox[dst * 4 + 1] = cobox[src * 4 + 1];
    sobox[dst * 4 + 2] = cobox[src * 4 + 2]; sobox[dst * 4 + 3] = cobox[src * 4 + 3];
}

// ---------------- sparse suppression edges: forward pairs (i<j) with IoU>0.7 ----------------
// IoU arithmetic identical to the previously-verified dense k_mask.
__global__ void k_edge(const float* __restrict__ sobox, u32* __restrict__ gE, u32* __restrict__ gPairs) {
    int n = blockIdx.z;
    int bi = blockIdx.x, bj = blockIdx.y;
    if (bj < bi) return;                         // forward-only (upper triangle)
    int i = bi * 64 + threadIdx.x;
    int j0 = bj * 64;
    __shared__ float cb[64][4];
    int jl = j0 + threadIdx.x;
    if (jl < KTOT) {
        cb[threadIdx.x][0] = sobox[(size_t)(n * KTOT + jl) * 4 + 0];
        cb[threadIdx.x][1] = sobox[(size_t)(n * KTOT + jl) * 4 + 1];
        cb[threadIdx.x][2] = sobox[(size_t)(n * KTOT + jl) * 4 + 2];
        cb[threadIdx.x][3] = sobox[(size_t)(n * KTOT + jl) * 4 + 3];
    } else {
        cb[threadIdx.x][0] = 0.f; cb[threadIdx.x][1] = 0.f;
        cb[threadIdx.x][2] = 0.f; cb[threadIdx.x][3] = 0.f;
    }
    __syncthreads();
    if (i >= KTOT) return;
    float x1 = sobox[(size_t)(n * KTOT + i) * 4 + 0];
    float y1 = sobox[(size_t)(n * KTOT + i) * 4 + 1];
    float x2 = sobox[(size_t)(n * KTOT + i) * 4 + 2];
    float y2 = sobox[(size_t)(n * KTOT + i) * 4 + 3];
    float areai = fmaxf(x2 - x1, 0.f) * fmaxf(y2 - y1, 0.f);
    int lim = KTOT - j0; if (lim > 64) lim = 64;
    for (int jj = 0; jj < lim; ++jj) {
        int j = j0 + jj;
        if (j <= i) continue;
        float bx1 = cb[jj][0], by1 = cb[jj][1], bx2 = cb[jj][2], by2 = cb[jj][3];
        float areaj = fmaxf(bx2 - bx1, 0.f) * fmaxf(by2 - by1, 0.f);
        float ltx = fmaxf(x1, bx1), lty = fmaxf(y1, by1);
        float rbx = fminf(x2, bx2), rby = fminf(y2, by2);
        float iw = fmaxf(rbx - ltx, 0.f), ih = fmaxf(rby - lty, 0.f);
        float inter = iw * ih;
        float iou = inter / (areai + areaj - inter + 1e-9f);
        if (iou > 0.7f) {
            u32 pos = atomicAdd(&gE[n], 1u);
            if (pos < ECAP) gPairs[(size_t)n * ECAP + pos] = ((u32)i << 13) | (u32)j;
        }
    }
}

// ---------------- greedy NMS sweep over sparse CSR (zero global mem on sweep path) ----------------
__global__ __launch_bounds__(256, 1) void k_nms(const float* __restrict__ ssc,
                      const float* __restrict__ sbox,
                      const u32* __restrict__ gE, const u32* __restrict__ gPairs,
                      u16* __restrict__ gEdges, float* __restrict__ out) {
    int n = blockIdx.x, tid = threadIdx.x;
    int lane = tid & 63, wv = tid >> 6;          // 4 waves
    __shared__ u32 cnt[KTOT];                    // 20 KB (count, then fill cursor)
    __shared__ u32 offs[KTOT + 1];               // 20 KB
    __shared__ u16 edges[LECAP];                 // 48 KB
    __shared__ u32 rem32[160];                   // dead bitmap (2 u32 per 64-word)
    __shared__ u32 colLo[64], colHi[64];
    __shared__ u32 scanb[256];
    __shared__ int picksS;

    // zero cnt + rem tail
    for (int i = tid; i < KTOT; i += 256) cnt[i] = 0;
    if (tid < 160) rem32[tid] = 0xFFFFFFFFu;     // default dead; real words overwritten
    __syncthreads();
    // dead-map init from scores (wave-parallel ballots)
    for (int w = wv; w < 79; w += 4) {
        int i = w * 64 + lane;
        bool dead = (i >= KTOT) || !(ssc[n * KTOT + i] > -INFINITY);
        u64 db = __ballot(dead);
        if (lane == 0) { rem32[2 * w] = (u32)db; rem32[2 * w + 1] = (u32)(db >> 32); }
    }
    __syncthreads();

    // ---- CSR build from global pair list ----
    int E = (int)gE[n]; if (E > ECAP) E = ECAP;
    for (int k = tid; k < E; k += 256) {
        u32 p = gPairs[(size_t)n * ECAP + k];
        atomicAdd(&cnt[p >> 13], 1u);
    }
    __syncthreads();
    // scan: 250 threads x 20 elems + block Hillis-Steele over totals
    u32 s = 0; int base = tid * 20;
    if (tid < 250) for (int q = 0; q < 20; ++q) s += cnt[base + q];
    scanb[tid] = s;
    __syncthreads();
    for (int off = 1; off < 256; off <<= 1) {
        u32 v = (tid >= off) ? scanb[tid - off] : 0;
        __syncthreads();
        scanb[tid] += v;
        __syncthreads();
    }
    u32 tbase = (tid == 0) ? 0u : scanb[tid - 1];
    if (tid < 250) {
        u32 run = tbase;
        for (int q = 0; q < 20; ++q) { offs[base + q] = run; run += cnt[base + q]; }
    }
    if (tid == 0) offs[KTOT] = scanb[255];
    __syncthreads();
    for (int i = tid; i < KTOT; i += 256) cnt[i] = 0;   // reuse as fill cursor
    __syncthreads();
    for (int k = tid; k < E; k += 256) {
        u32 p = gPairs[(size_t)n * ECAP + k];
        u32 src = p >> 13, dst = p & 0x1FFFu;
        u32 slot = offs[src] + atomicAdd(&cnt[src], 1u);
        if (slot < LECAP) edges[slot] = (u16)dst;
        else gEdges[(size_t)n * ECAP + slot] = (u16)dst;
    }
    __syncthreads();

    // ---- wave-0 sweep: rank order, no global memory on the critical path ----
    if (wv == 0) {
        int picks = 0;
        for (int w = 0; w < 79 && picks < 1000; ++w) {
            u64 rw = ((u64)rem32[2 * w + 1] << 32) | rem32[2 * w];
            u64 alive = ~rw;
            if (alive == 0ULL) continue;
            int c = w * 64 + lane;
            bool amAlive = ((alive >> lane) & 1ULL) != 0ULL;
            int e0 = 0, e1 = 0;
            if (amAlive) { e0 = (int)offs[c]; e1 = (int)offs[c + 1]; }
            // intra-word suppression bits (rare)
            colLo[lane] = 0; colHi[lane] = 0;
            bool anyIntra = false;
            for (int k = e0; k < e1; ++k) {
                int dst = (k < LECAP) ? (int)edges[k] : (int)gEdges[(size_t)n * ECAP + k];
                if ((dst >> 6) == w) {
                    if (lane < 32) atomicOr(&colLo[dst & 63], 1u << lane);
                    else           atomicOr(&colHi[dst & 63], 1u << (lane - 32));
                    anyIntra = true;
                }
            }
            u64 cm;
            if (__ballot(anyIntra) == 0ULL) {
                cm = alive;                                   // fast path: no intra-word conflicts
            } else {
                u64 col = ((u64)colHi[lane] << 32) | colLo[lane];
                cm = 0ULL;
                for (int e = 0; e < 64; ++e) {
                    if (!((alive >> e) & 1ULL)) continue;
                    u64 ce = __shfl(col, e);
                    if ((cm & ce) == 0ULL) cm |= (1ULL << e);
                }
            }
            int allowed = 1000 - picks;
            int ncom = __popcll(cm);
            while (ncom > allowed) { cm &= ~(1ULL << (63 - __clzll(cm))); --ncom; }
            // committed lanes: write output + apply forward kills
            if ((cm >> lane) & 1ULL) {
                int pos = picks + (int)__popcll(cm & ((1ULL << lane) - 1ULL));
                const float* bp = &sbox[(size_t)(n * KTOT + c) * 4];
                float* op = &out[(n * 1000 + pos) * 5];
                op[0] = bp[0]; op[1] = bp[1]; op[2] = bp[2]; op[3] = bp[3];
                op[4] = ssc[n * KTOT + c];
                for (int k = e0; k < e1; ++k) {
                    int dst = (k < LECAP) ? (int)edges[k] : (int)gEdges[(size_t)n * ECAP + k];
                    atomicOr(&rem32[dst >> 5], 1u << (dst & 31));
                }
            }
            picks += ncom;
        }
        if (lane == 0) picksS = picks;
    }
    __syncthreads();
    // zero-fill remaining output rows
    int picksF = picksS;
    int basec = (n * 1000 + picksF) * 5, cntz = (1000 - picksF) * 5;
    for (int t = tid; t < cntz; t += 256) out[basec + t] = 0.f;
}

// ---------------- workspace layout ----------------
constexpr size_t OFF_HIST   = 0;                                       // zeroed region start
constexpr size_t OFF_GCNT   = OFF_HIST + 10 * BINS * 4;                // 81920
constexpr size_t OFF_ECNT   = OFF_GCNT + 64;
constexpr size_t OFF_GEC    = OFF_ECNT + 64;                           // edge counters (2 u32)
constexpr size_t ZERO_WORDS = (10 * BINS * 4 + 192) / 4;               // hist + gcnt + ecnt + gec
constexpr size_t OFF_BINB   = OFF_GEC + 64;
constexpr size_t OFF_KNEED  = OFF_BINB + 64;
constexpr size_t OFF_G0     = OFF_KNEED + 64;
constexpr size_t OFF_SEL    = OFF_G0 + 64;
constexpr size_t OFF_EQ     = OFF_SEL + 10 * K_PER_LVL * 4;            // 8-aligned
constexpr size_t OFF_KEY64  = OFF_EQ + (size_t)10 * EQ_CAP * 8;
constexpr size_t OFF_CSC    = OFF_KEY64 + (size_t)NIMG * KTOT * 8;
constexpr size_t OFF_CBOX   = OFF_CSC + (size_t)NIMG * KTOT * 4;
constexpr size_t OFF_COBOX  = OFF_CBOX + (size_t)NIMG * KTOT * 16;
constexpr size_t OFF_SSC    = OFF_COBOX + (size_t)NIMG * KTOT * 16;
constexpr size_t OFF_SBOX   = OFF_SSC + (size_t)NIMG * KTOT * 4;
constexpr size_t OFF_SOBOX  = OFF_SBOX + (size_t)NIMG * KTOT * 16;
constexpr size_t OFF_PAIRS  = OFF_SOBOX + (size_t)NIMG * KTOT * 16;    // u32[NIMG*ECAP]
constexpr size_t OFF_ESPILL = OFF_PAIRS + (size_t)NIMG * ECAP * 4;     // u16[NIMG*ECAP]
constexpr size_t WS_NEEDED  = OFF_ESPILL + (size_t)NIMG * ECAP * 2;    // ~2.3 MB

extern "C" void kernel_launch(void* const* d_in, const int* in_sizes, int n_in,
                              void* d_out, int out_size, void* d_ws, size_t ws_size,
                              hipStream_t stream) {
    if (ws_size < WS_NEEDED) return;

    // Detect input ordering from sizes: dict order interleaves (obj0,box0,...)
    bool dictOrder = (in_sizes[1] > in_sizes[0]);
    Ptrs P;
    for (int l = 0; l < 5; ++l) {
        P.o[l] = (const float*)d_in[dictOrder ? (2 * l)     : l];
        P.b[l] = (const float*)d_in[dictOrder ? (2 * l + 1) : (5 + l)];
    }
    char* ws = (char*)d_ws;
    u32*   hist   = (u32*)(ws + OFF_HIST);
    u32*   gcnt   = (u32*)(ws + OFF_GCNT);
    u32*   ecnt   = (u32*)(ws + OFF_ECNT);
    u32*   gec    = (u32*)(ws + OFF_GEC);
    int*   binB   = (int*)(ws + OFF_BINB);
    int*   kneed  = (int*)(ws + OFF_KNEED);
    int*   g0     = (int*)(ws + OFF_G0);
    int*   sel    = (int*)(ws + OFF_SEL);
    u64*   eq     = (u64*)(ws + OFF_EQ);
    u64*   key64  = (u64*)(ws + OFF_KEY64);
    float* csc    = (float*)(ws + OFF_CSC);
    float* cbox   = (float*)(ws + OFF_CBOX);
    float* cobox  = (float*)(ws + OFF_COBOX);
    float* ssc    = (float*)(ws + OFF_SSC);
    float* sbox   = (float*)(ws + OFF_SBOX);
    float* sobox  = (float*)(ws + OFF_SOBOX);
    u32*   pairs  = (u32*)(ws + OFF_PAIRS);
    u16*   espill = (u16*)(ws + OFF_ESPILL);
    float* out    = (float*)d_out;

    k_zero<<<dim3(21), 256, 0, stream>>>(hist, (int)ZERO_WORDS);       // hist + counters + edge counters
    k_hist<<<dim3(32, 10), 256, 0, stream>>>(P, hist);
    k_resolve<<<10, 256, 0, stream>>>(hist, binB, kneed, g0);
    k_compact<<<dim3(64, 10), 256, 0, stream>>>(P, binB, gcnt, ecnt, sel, eq);
    k_eqsel<<<10, 256, 0, stream>>>(ecnt, kneed, g0, eq, sel);
    k_feat<<<dim3((NIMG * KTOT + 255) / 256), 256, 0, stream>>>(P, sel, key64, csc, cbox, cobox);
    k_rank<<<dim3((KTOT + 255) / 256, NIMG), 256, 0, stream>>>(key64, csc, cbox, cobox, ssc, sbox, sobox);
    k_edge<<<dim3(79, 79, NIMG), 64, 0, stream>>>(sobox, gec, pairs);
    k_nms<<<NIMG, 256, 0, stream>>>(ssc, sbox, gec, pairs, espill, out);
}

// Round 10
// 280.114 us; speedup vs baseline: 3.4918x; 1.1826x over previous
//
#include <hip/hip_runtime.h>
#include <cmath>

#pragma clang fp contract(off)

typedef unsigned int u32;
typedef unsigned short u16;
typedef unsigned long long u64;

#define K_PER_LVL 1000
#define KTOT 5000            // 5 levels * 1000
#define NIMG 2
#define BINS 2048            // histogram bins = top 11 bits of fkey
#define BIN_SHIFT 21
#define EQ_CAP 2048
#define ECAP 32768           // max suppression edges per image (est ~4k; 8x margin)
#define LECAP 24576          // edges held in LDS; overflow spills to global
#define CBUF 1024            // per-block staging capacity in k_compact

__constant__ int c_LG[5] = {512, 256, 128, 64, 32};      // grid dim (square)
__constant__ int c_LS[5] = {4, 8, 16, 32, 64};           // stride
__constant__ int c_LZ[5] = {32, 64, 128, 256, 512};      // anchor size
__constant__ int c_LM[5] = {786432, 196608, 49152, 12288, 3072}; // 3*G*G

struct Ptrs { const float* o[5]; const float* b[5]; };

// monotone float -> uint key (larger float => larger key)
__device__ inline u32 fkey(float f) {
    u32 u = __float_as_uint(f);
    return (u & 0x80000000u) ? ~u : (u | 0x80000000u);
}

// ---------------- zero hist + counters ----------------
__global__ __launch_bounds__(256) void k_zero(u32* __restrict__ z, int nwords) {
    int i = blockIdx.x * 256 + threadIdx.x;
    int stride = gridDim.x * 256;
    for (; i < nwords; i += stride) z[i] = 0;
}

// ---------------- one-pass 2048-bin histogram (float4 loads, LDS pre-agg) ----------------
__global__ __launch_bounds__(256) void k_hist(Ptrs P, u32* __restrict__ hist) {
    int p = blockIdx.y; int l = p % 5; int n = p / 5;
    int M4 = c_LM[l] >> 2;
    const float4* base = (const float4*)(P.o[l] + (size_t)n * c_LM[l]);
    __shared__ u32 lh[BINS];
    for (int i = threadIdx.x; i < BINS; i += 256) lh[i] = 0;
    __syncthreads();
    int stride = gridDim.x * 256;
    for (int i = blockIdx.x * 256 + threadIdx.x; i < M4; i += stride) {
        float4 v = base[i];
        atomicAdd(&lh[fkey(v.x) >> BIN_SHIFT], 1u);
        atomicAdd(&lh[fkey(v.y) >> BIN_SHIFT], 1u);
        atomicAdd(&lh[fkey(v.z) >> BIN_SHIFT], 1u);
        atomicAdd(&lh[fkey(v.w) >> BIN_SHIFT], 1u);
    }
    __syncthreads();
    for (int i = threadIdx.x; i < BINS; i += 256) {
        u32 c = lh[i];
        if (c) atomicAdd(&hist[p * BINS + i], c);
    }
}

// ---------------- resolve: threshold bin B, G = #(keys above B), KF = 1000 - G ----------------
__global__ __launch_bounds__(256) void k_resolve(const u32* __restrict__ hist,
                                                 int* __restrict__ binB, int* __restrict__ kneed,
                                                 int* __restrict__ g0) {
    int p = blockIdx.x, t = threadIdx.x;
    __shared__ u32 lh[BINS];
    __shared__ u32 seg[256];
    for (int i = t; i < BINS; i += 256) lh[i] = hist[p * BINS + i];
    __syncthreads();
    u32 s = 0;
    for (int q = 0; q < 8; ++q) s += lh[t * 8 + q];
    seg[t] = s;
    __syncthreads();
    if (t == 0) {
        u32 G = 0; int B = 0;
        for (int sg = 255; sg >= 0; --sg) {
            if (G + seg[sg] >= (u32)K_PER_LVL) {
                for (int b = sg * 8 + 7; b >= sg * 8; --b) {
                    u32 c = lh[b];
                    if (G + c >= (u32)K_PER_LVL) { B = b; break; }
                    G += c;
                }
                break;
            }
            G += seg[sg];
        }
        binB[p] = B;
        kneed[p] = K_PER_LVL - (int)G;   // KF taken from boundary bin
        g0[p] = (int)G;                  // count strictly above bin B
    }
}

// ---------------- compact: block-local LDS staging, ONE reservation atomic per block ----------------
// (round-9 profile: ~20k value-returning global atomics on 10 hot counters
// ping-ponged across XCD L2s -> 61 us. Staging cuts global atomics ~15x;
// sel/eq content order is arbitrary by design - keys define the total order.)
__global__ __launch_bounds__(256) void k_compact(Ptrs P, const int* __restrict__ binB,
                                                 u32* gcnt, u32* ecnt,
                                                 int* __restrict__ sel, u64* __restrict__ eq) {
    int p = blockIdx.y; int l = p % 5; int n = p / 5;
    int M4 = c_LM[l] >> 2; int gg = c_LM[l] / 3;
    const float4* base = (const float4*)(P.o[l] + (size_t)n * c_LM[l]);
    int B = binB[p];
    __shared__ u32 lsel[CBUF];
    __shared__ u64 leq[CBUF];
    __shared__ u32 cSel, cEq, baseSel, baseEq;
    if (threadIdx.x == 0) { cSel = 0; cEq = 0; }
    __syncthreads();
    int stride = gridDim.x * 256;
    for (int i4 = blockIdx.x * 256 + threadIdx.x; i4 < M4; i4 += stride) {
        float4 v = base[i4];
        float vv[4] = {v.x, v.y, v.z, v.w};
        #pragma unroll
        for (int q = 0; q < 4; ++q) {
            u32 k = fkey(vv[q]);
            int bin = (int)(k >> BIN_SHIFT);
            if (bin < B) continue;
            int i = i4 * 4 + q;
            // input linear i = a*gg + pix ; flattened m = pix*3 + a  (h,w,a order)
            int a = i / gg; int pix = i - a * gg; int m = pix * 3 + a;
            if (bin > B) {
                u32 t = atomicAdd(&cSel, 1u);
                if (t < CBUF) lsel[t] = (u32)m;
                else { u32 pos = atomicAdd(&gcnt[p], 1u); sel[p * K_PER_LVL + pos] = m; }
            } else {
                u64 pk = ((u64)k << 20) | (u64)(0xFFFFFu ^ (u32)m);
                u32 t = atomicAdd(&cEq, 1u);
                if (t < CBUF) leq[t] = pk;
                else { u32 e = atomicAdd(&ecnt[p], 1u); if (e < EQ_CAP) eq[(size_t)p * EQ_CAP + e] = pk; }
            }
        }
    }
    __syncthreads();
    if (threadIdx.x == 0) {
        u32 ns = cSel < CBUF ? cSel : CBUF;
        u32 ne = cEq < CBUF ? cEq : CBUF;
        baseSel = ns ? atomicAdd(&gcnt[p], ns) : 0u;
        baseEq  = ne ? atomicAdd(&ecnt[p], ne) : 0u;
    }
    __syncthreads();
    u32 ns = cSel < CBUF ? cSel : CBUF;
    u32 ne = cEq < CBUF ? cEq : CBUF;
    for (u32 i = threadIdx.x; i < ns; i += 256) sel[p * K_PER_LVL + baseSel + i] = (int)lsel[i];
    for (u32 i = threadIdx.x; i < ne; i += 256) {
        u32 slot = baseEq + i;
        if (slot < EQ_CAP) eq[(size_t)p * EQ_CAP + slot] = leq[i];
    }
}

// ---------------- boundary bin: rank-by-count selection (keys unique), take KF lowest ranks ----------------
__global__ __launch_bounds__(256) void k_eqsel(const u32* __restrict__ ecnt, const int* __restrict__ kneed,
                                               const int* __restrict__ g0,
                                               const u64* __restrict__ eq, int* __restrict__ sel) {
    int p = blockIdx.x, t = threadIdx.x;
    int E = (int)ecnt[p]; if (E > EQ_CAP) E = EQ_CAP;
    int KF = kneed[p]; int G0 = g0[p];
    __shared__ u64 a[EQ_CAP];
    for (int i = t; i < E; i += 256) a[i] = eq[(size_t)p * EQ_CAP + i];
    __syncthreads();
    u64 mine[8]; int rk[8];
    #pragma unroll
    for (int q = 0; q < 8; ++q) {
        int i = t + q * 256;
        mine[q] = (i < E) ? a[i] : 0ULL;
        rk[q] = 0;
    }
    for (int j = 0; j < E; ++j) {
        u64 v = a[j];                            // uniform index -> LDS broadcast
        #pragma unroll
        for (int q = 0; q < 8; ++q) rk[q] += (v > mine[q]) ? 1 : 0;
    }
    #pragma unroll
    for (int q = 0; q < 8; ++q) {
        int i = t + q * 256;
        if (i < E && rk[q] < KF) {
            int m = (int)(0xFFFFFu ^ (u32)(mine[q] & 0xFFFFFu));
            sel[p * K_PER_LVL + G0 + rk[q]] = m;
        }
    }
}

// ---------------- featurize: anchors + decode + clip + score + 64b order key ----------------
__global__ void k_feat(Ptrs P, const int* __restrict__ sel, u64* __restrict__ key64,
                       float* __restrict__ csc, float* __restrict__ cbox, float* __restrict__ cobox) {
    int tid = blockIdx.x * 256 + threadIdx.x;
    if (tid >= NIMG * KTOT) return;
    int p = tid / K_PER_LVL, s = tid - p * K_PER_LVL;
    int n = p / 5, l = p % 5;
    int G = c_LG[l], S = c_LS[l], Z = c_LZ[l];
    int gg = G * G;
    int m = sel[p * K_PER_LVL + s];
    int a = m % 3; int pix = m / 3; int h = pix / G; int w = pix - h * G;

    // anchor base: hr=sqrt(ar), wr=1/hr, round-half-even (matches jnp f32)
    const float ars[3] = {0.5f, 1.0f, 2.0f};
    float ar = ars[a];
    float hr = sqrtf(ar), wr = 1.0f / hr;
    float wsz = wr * (float)Z, hsz = hr * (float)Z;
    float bx1 = rintf(-0.5f * wsz), by1 = rintf(-0.5f * hsz);
    float bx2 = rintf(0.5f * wsz),  by2 = rintf(0.5f * hsz);
    float sx = (float)(w * S), sy = (float)(h * S);
    float ax1 = sx + bx1, ay1 = sy + by1, ax2 = sx + bx2, ay2 = sy + by2;
    float wa = ax2 - ax1, ha = ay2 - ay1;
    float cxa = ax1 + 0.5f * wa, cya = ay1 + 0.5f * ha;

    const float* bb = P.b[l] + (size_t)n * 12 * gg;
    float dx = bb[(a * 4 + 0) * gg + pix];
    float dy = bb[(a * 4 + 1) * gg + pix];
    const float CLIPV = 4.135166556742356f;  // log(1000/16)
    float dw = fminf(bb[(a * 4 + 2) * gg + pix], CLIPV);
    float dh = fminf(bb[(a * 4 + 3) * gg + pix], CLIPV);
    float cx = dx * wa + cxa, cy = dy * ha + cya;
    float ww = expf(dw) * wa, hh = expf(dh) * ha;
    float x1 = cx - 0.5f * ww, y1 = cy - 0.5f * hh;
    float x2 = cx + 0.5f * ww, y2 = cy + 0.5f * hh;
    x1 = fminf(fmaxf(x1, 0.f), 2048.f);
    y1 = fminf(fmaxf(y1, 0.f), 2048.f);
    x2 = fminf(fmaxf(x2, 0.f), 2048.f);
    y2 = fminf(fmaxf(y2, 0.f), 2048.f);

    float raw = P.o[l][(size_t)n * 3 * gg + a * gg + pix];
    float sc = 1.0f / (1.0f + expf(-raw));
    bool keep = (x2 - x1 >= 1e-3f) && (y2 - y1 >= 1e-3f) && (sc > 0.0f);

    int slot = n * KTOT + l * K_PER_LVL + s;
    // total order key: raw desc, then (level asc, m asc) == reference concat-position order
    u32 tb = ((u32)l << 20) | (u32)m;          // m < 2^20, l < 8  -> 23 bits, unique
    u32 kk = keep ? fkey(raw) : 0u;            // invalid sinks below every valid (finite raw)
    key64[slot] = ((u64)kk << 23) | (u64)(tb ^ 0x7FFFFFu);

    csc[slot] = keep ? sc : -INFINITY;
    cbox[slot * 4 + 0] = x1; cbox[slot * 4 + 1] = y1;
    cbox[slot * 4 + 2] = x2; cbox[slot * 4 + 3] = y2;
    float off = 4097.0f * (float)l;            // lvl * (W+H+1), batched_nms offset
    cobox[slot * 4 + 0] = x1 + off; cobox[slot * 4 + 1] = y1 + off;
    cobox[slot * 4 + 2] = x2 + off; cobox[slot * 4 + 3] = y2 + off;
}

// ---------------- exact rank by counting (LDS-staged keys), scatter ----------------
__global__ __launch_bounds__(256) void k_rank(const u64* __restrict__ key64, const float* __restrict__ csc,
                       const float* __restrict__ cbox, const float* __restrict__ cobox,
                       float* __restrict__ ssc, float* __restrict__ sbox, float* __restrict__ sobox) {
    int n = blockIdx.y;
    __shared__ u64 kk[KTOT];                     // 40 KB
    for (int t = threadIdx.x; t < KTOT; t += 256) kk[t] = key64[(size_t)n * KTOT + t];
    __syncthreads();
    int i = blockIdx.x * 256 + threadIdx.x;
    if (i >= KTOT) return;
    u64 ki = kk[i];
    int rank = 0;
    for (int j = 0; j < KTOT; ++j) rank += (kk[j] > ki) ? 1 : 0;   // lockstep j -> LDS broadcast
    int src = n * KTOT + i, dst = n * KTOT + rank;
    ssc[dst] = csc[src];
    sbox[dst * 4 + 0] = cbox[src * 4 + 0]; sbox[dst * 4 + 1] = cbox[src * 4 + 1];
    sbox[dst * 4 + 2] = cbox[src * 4 + 2]; sbox[dst * 4 + 3] = cbox[src * 4 + 3];
    sobox[dst * 4 + 0] = cobox[src * 4 + 0]; sobox[dst * 4 + 1] = cobox[src * 4 + 1];
    sobox[dst * 4 + 2] = cobox[src * 4 + 2]; sobox[dst * 4 + 3] = cobox[src * 4 + 3];
}

// ---------------- sparse suppression edges: forward pairs (i<j) with IoU>0.7 ----------------
__global__ void k_edge(const float* __restrict__ sobox, u32* __restrict__ gE, u32* __restrict__ gPairs) {
    int n = blockIdx.z;
    int bi = blockIdx.x, bj = blockIdx.y;
    if (bj < bi) return;                         // forward-only (upper triangle)
    int i = bi * 64 + threadIdx.x;
    int j0 = bj * 64;
    __shared__ float cb[64][4];
    int jl = j0 + threadIdx.x;
    if (jl < KTOT) {
        cb[threadIdx.x][0] = sobox[(size_t)(n * KTOT + jl) * 4 + 0];
        cb[threadIdx.x][1] = sobox[(size_t)(n * KTOT + jl) * 4 + 1];
        cb[threadIdx.x][2] = sobox[(size_t)(n * KTOT + jl) * 4 + 2];
        cb[threadIdx.x][3] = sobox[(size_t)(n * KTOT + jl) * 4 + 3];
    } else {
        cb[threadIdx.x][0] = 0.f; cb[threadIdx.x][1] = 0.f;
        cb[threadIdx.x][2] = 0.f; cb[threadIdx.x][3] = 0.f;
    }
    __syncthreads();
    if (i >= KTOT) return;
    float x1 = sobox[(size_t)(n * KTOT + i) * 4 + 0];
    float y1 = sobox[(size_t)(n * KTOT + i) * 4 + 1];
    float x2 = sobox[(size_t)(n * KTOT + i) * 4 + 2];
    float y2 = sobox[(size_t)(n * KTOT + i) * 4 + 3];
    float areai = fmaxf(x2 - x1, 0.f) * fmaxf(y2 - y1, 0.f);
    int lim = KTOT - j0; if (lim > 64) lim = 64;
    for (int jj = 0; jj < lim; ++jj) {
        int j = j0 + jj;
        if (j <= i) continue;
        float bx1 = cb[jj][0], by1 = cb[jj][1], bx2 = cb[jj][2], by2 = cb[jj][3];
        float areaj = fmaxf(bx2 - bx1, 0.f) * fmaxf(by2 - by1, 0.f);
        float ltx = fmaxf(x1, bx1), lty = fmaxf(y1, by1);
        float rbx = fminf(x2, bx2), rby = fminf(y2, by2);
        float iw = fmaxf(rbx - ltx, 0.f), ih = fmaxf(rby - lty, 0.f);
        float inter = iw * ih;
        float iou = inter / (areai + areaj - inter + 1e-9f);
        if (iou > 0.7f) {
            u32 pos = atomicAdd(&gE[n], 1u);
            if (pos < ECAP) gPairs[(size_t)n * ECAP + pos] = ((u32)i << 13) | (u32)j;
        }
    }
}

// ---------------- greedy NMS sweep over sparse CSR (zero global mem on sweep path) ----------------
__global__ __launch_bounds__(256, 1) void k_nms(const float* __restrict__ ssc,
                      const float* __restrict__ sbox,
                      const u32* __restrict__ gE, const u32* __restrict__ gPairs,
                      u16* __restrict__ gEdges, float* __restrict__ out) {
    int n = blockIdx.x, tid = threadIdx.x;
    int lane = tid & 63, wv = tid >> 6;          // 4 waves
    __shared__ u32 cnt[KTOT];                    // 20 KB (count, then fill cursor)
    __shared__ u32 offs[KTOT + 1];               // 20 KB
    __shared__ u16 edges[LECAP];                 // 48 KB
    __shared__ u32 rem32[160];                   // dead bitmap (2 u32 per 64-word)
    __shared__ u32 colLo[64], colHi[64];
    __shared__ u32 scanb[256];
    __shared__ int picksS;

    // zero cnt + rem tail
    for (int i = tid; i < KTOT; i += 256) cnt[i] = 0;
    if (tid < 160) rem32[tid] = 0xFFFFFFFFu;     // default dead; real words overwritten
    __syncthreads();
    // dead-map init from scores (wave-parallel ballots)
    for (int w = wv; w < 79; w += 4) {
        int i = w * 64 + lane;
        bool dead = (i >= KTOT) || !(ssc[n * KTOT + i] > -INFINITY);
        u64 db = __ballot(dead);
        if (lane == 0) { rem32[2 * w] = (u32)db; rem32[2 * w + 1] = (u32)(db >> 32); }
    }
    __syncthreads();

    // ---- CSR build from global pair list ----
    int E = (int)gE[n]; if (E > ECAP) E = ECAP;
    for (int k = tid; k < E; k += 256) {
        u32 p = gPairs[(size_t)n * ECAP + k];
        atomicAdd(&cnt[p >> 13], 1u);
    }
    __syncthreads();
    // scan: 250 threads x 20 elems + block Hillis-Steele over totals
    u32 s = 0; int base = tid * 20;
    if (tid < 250) for (int q = 0; q < 20; ++q) s += cnt[base + q];
    scanb[tid] = s;
    __syncthreads();
    for (int off = 1; off < 256; off <<= 1) {
        u32 v = (tid >= off) ? scanb[tid - off] : 0;
        __syncthreads();
        scanb[tid] += v;
        __syncthreads();
    }
    u32 tbase = (tid == 0) ? 0u : scanb[tid - 1];
    if (tid < 250) {
        u32 run = tbase;
        for (int q = 0; q < 20; ++q) { offs[base + q] = run; run += cnt[base + q]; }
    }
    if (tid == 0) offs[KTOT] = scanb[255];
    __syncthreads();
    for (int i = tid; i < KTOT; i += 256) cnt[i] = 0;   // reuse as fill cursor
    __syncthreads();
    for (int k = tid; k < E; k += 256) {
        u32 p = gPairs[(size_t)n * ECAP + k];
        u32 src = p >> 13, dst = p & 0x1FFFu;
        u32 slot = offs[src] + atomicAdd(&cnt[src], 1u);
        if (slot < LECAP) edges[slot] = (u16)dst;
        else gEdges[(size_t)n * ECAP + slot] = (u16)dst;
    }
    __syncthreads();

    // ---- wave-0 sweep: rank order, no global memory on the critical path ----
    if (wv == 0) {
        int picks = 0;
        for (int w = 0; w < 79 && picks < 1000; ++w) {
            u64 rw = ((u64)rem32[2 * w + 1] << 32) | rem32[2 * w];
            u64 alive = ~rw;
            if (alive == 0ULL) continue;
            int c = w * 64 + lane;
            bool amAlive = ((alive >> lane) & 1ULL) != 0ULL;
            int e0 = 0, e1 = 0;
            if (amAlive) { e0 = (int)offs[c]; e1 = (int)offs[c + 1]; }
            // intra-word suppression bits (rare)
            colLo[lane] = 0; colHi[lane] = 0;
            bool anyIntra = false;
            for (int k = e0; k < e1; ++k) {
                int dst = (k < LECAP) ? (int)edges[k] : (int)gEdges[(size_t)n * ECAP + k];
                if ((dst >> 6) == w) {
                    if (lane < 32) atomicOr(&colLo[dst & 63], 1u << lane);
                    else           atomicOr(&colHi[dst & 63], 1u << (lane - 32));
                    anyIntra = true;
                }
            }
            u64 cm;
            if (__ballot(anyIntra) == 0ULL) {
                cm = alive;                                   // fast path: no intra-word conflicts
            } else {
                u64 col = ((u64)colHi[lane] << 32) | colLo[lane];
                cm = 0ULL;
                for (int e = 0; e < 64; ++e) {
                    if (!((alive >> e) & 1ULL)) continue;
                    u64 ce = __shfl(col, e);
                    if ((cm & ce) == 0ULL) cm |= (1ULL << e);
                }
            }
            int allowed = 1000 - picks;
            int ncom = __popcll(cm);
            while (ncom > allowed) { cm &= ~(1ULL << (63 - __clzll(cm))); --ncom; }
            // committed lanes: write output + apply forward kills
            if ((cm >> lane) & 1ULL) {
                int pos = picks + (int)__popcll(cm & ((1ULL << lane) - 1ULL));
                const float* bp = &sbox[(size_t)(n * KTOT + c) * 4];
                float* op = &out[(n * 1000 + pos) * 5];
                op[0] = bp[0]; op[1] = bp[1]; op[2] = bp[2]; op[3] = bp[3];
                op[4] = ssc[n * KTOT + c];
                for (int k = e0; k < e1; ++k) {
                    int dst = (k < LECAP) ? (int)edges[k] : (int)gEdges[(size_t)n * ECAP + k];
                    atomicOr(&rem32[dst >> 5], 1u << (dst & 31));
                }
            }
            picks += ncom;
        }
        if (lane == 0) picksS = picks;
    }
    __syncthreads();
    // zero-fill remaining output rows
    int picksF = picksS;
    int basec = (n * 1000 + picksF) * 5, cntz = (1000 - picksF) * 5;
    for (int t = tid; t < cntz; t += 256) out[basec + t] = 0.f;
}

// ---------------- workspace layout ----------------
constexpr size_t OFF_HIST   = 0;                                       // zeroed region start
constexpr size_t OFF_GCNT   = OFF_HIST + 10 * BINS * 4;                // 81920
constexpr size_t OFF_ECNT   = OFF_GCNT + 64;
constexpr size_t OFF_GEC    = OFF_ECNT + 64;                           // edge counters (2 u32)
constexpr size_t ZERO_WORDS = (10 * BINS * 4 + 192) / 4;               // hist + gcnt + ecnt + gec
constexpr size_t OFF_BINB   = OFF_GEC + 64;
constexpr size_t OFF_KNEED  = OFF_BINB + 64;
constexpr size_t OFF_G0     = OFF_KNEED + 64;
constexpr size_t OFF_SEL    = OFF_G0 + 64;
constexpr size_t OFF_EQ     = OFF_SEL + 10 * K_PER_LVL * 4;            // 8-aligned
constexpr size_t OFF_KEY64  = OFF_EQ + (size_t)10 * EQ_CAP * 8;
constexpr size_t OFF_CSC    = OFF_KEY64 + (size_t)NIMG * KTOT * 8;
constexpr size_t OFF_CBOX   = OFF_CSC + (size_t)NIMG * KTOT * 4;
constexpr size_t OFF_COBOX  = OFF_CBOX + (size_t)NIMG * KTOT * 16;
constexpr size_t OFF_SSC    = OFF_COBOX + (size_t)NIMG * KTOT * 16;
constexpr size_t OFF_SBOX   = OFF_SSC + (size_t)NIMG * KTOT * 4;
constexpr size_t OFF_SOBOX  = OFF_SBOX + (size_t)NIMG * KTOT * 16;
constexpr size_t OFF_PAIRS  = OFF_SOBOX + (size_t)NIMG * KTOT * 16;    // u32[NIMG*ECAP]
constexpr size_t OFF_ESPILL = OFF_PAIRS + (size_t)NIMG * ECAP * 4;     // u16[NIMG*ECAP]
constexpr size_t WS_NEEDED  = OFF_ESPILL + (size_t)NIMG * ECAP * 2;    // ~2.3 MB

extern "C" void kernel_launch(void* const* d_in, const int* in_sizes, int n_in,
                              void* d_out, int out_size, void* d_ws, size_t ws_size,
                              hipStream_t stream) {
    if (ws_size < WS_NEEDED) return;

    // Detect input ordering from sizes: dict order interleaves (obj0,box0,...)
    bool dictOrder = (in_sizes[1] > in_sizes[0]);
    Ptrs P;
    for (int l = 0; l < 5; ++l) {
        P.o[l] = (const float*)d_in[dictOrder ? (2 * l)     : l];
        P.b[l] = (const float*)d_in[dictOrder ? (2 * l + 1) : (5 + l)];
    }
    char* ws = (char*)d_ws;
    u32*   hist   = (u32*)(ws + OFF_HIST);
    u32*   gcnt   = (u32*)(ws + OFF_GCNT);
    u32*   ecnt   = (u32*)(ws + OFF_ECNT);
    u32*   gec    = (u32*)(ws + OFF_GEC);
    int*   binB   = (int*)(ws + OFF_BINB);
    int*   kneed  = (int*)(ws + OFF_KNEED);
    int*   g0     = (int*)(ws + OFF_G0);
    int*   sel    = (int*)(ws + OFF_SEL);
    u64*   eq     = (u64*)(ws + OFF_EQ);
    u64*   key64  = (u64*)(ws + OFF_KEY64);
    float* csc    = (float*)(ws + OFF_CSC);
    float* cbox   = (float*)(ws + OFF_CBOX);
    float* cobox  = (float*)(ws + OFF_COBOX);
    float* ssc    = (float*)(ws + OFF_SSC);
    float* sbox   = (float*)(ws + OFF_SBOX);
    float* sobox  = (float*)(ws + OFF_SOBOX);
    u32*   pairs  = (u32*)(ws + OFF_PAIRS);
    u16*   espill = (u16*)(ws + OFF_ESPILL);
    float* out    = (float*)d_out;

    k_zero<<<dim3(21), 256, 0, stream>>>(hist, (int)ZERO_WORDS);       // hist + counters + edge counters
    k_hist<<<dim3(32, 10), 256, 0, stream>>>(P, hist);
    k_resolve<<<10, 256, 0, stream>>>(hist, binB, kneed, g0);
    k_compact<<<dim3(64, 10), 256, 0, stream>>>(P, binB, gcnt, ecnt, sel, eq);
    k_eqsel<<<10, 256, 0, stream>>>(ecnt, kneed, g0, eq, sel);
    k_feat<<<dim3((NIMG * KTOT + 255) / 256), 256, 0, stream>>>(P, sel, key64, csc, cbox, cobox);
    k_rank<<<dim3((KTOT + 255) / 256, NIMG), 256, 0, stream>>>(key64, csc, cbox, cobox, ssc, sbox, sobox);
    k_edge<<<dim3(79, 79, NIMG), 64, 0, stream>>>(sobox, gec, pairs);
    k_nms<<<NIMG, 256, 0, stream>>>(ssc, sbox, gec, pairs, espill, out);
}